// Round 9
// baseline (869.775 us; speedup 1.0000x reference)
//
#include <hip/hip_runtime.h>
#include <hip/hip_bf16.h>
#include <stdint.h>

#define NB 16
#define NN 2048
#define NC 64
#define NH 128
#define NK 16
#define NS (NB*NN)
#define NSK (NS*NK)
#define EPSV 1e-5f

typedef __attribute__((ext_vector_type(8))) short short8;
typedef __attribute__((ext_vector_type(8))) _Float16 half8;
typedef __attribute__((ext_vector_type(8))) unsigned short ushort8;
typedef __attribute__((ext_vector_type(4))) float f32x4;

__device__ __forceinline__ unsigned short f2bf(float x) {
  union { float f; unsigned u; } v; v.f = x;
  unsigned r = v.u + 0x7fffu + ((v.u >> 16) & 1u);
  return (unsigned short)(r >> 16);
}

__device__ __forceinline__ unsigned orderf(float f) {
  unsigned u = __float_as_uint(f);
  return u ^ ((unsigned)((int)u >> 31) | 0x80000000u);
}

__device__ __forceinline__ float unorderf(unsigned whi) {
  return (whi == 0xffffffffu) ? __builtin_inff()
       : __uint_as_float((whi & 0x80000000u) ? (whi ^ 0x80000000u) : ~whi);
}

__device__ __forceinline__ unsigned long long shfl_xor_u64(unsigned long long v, int m) {
  unsigned lo = (unsigned)(v & 0xffffffffull);
  unsigned hi = (unsigned)(v >> 32);
  lo = __shfl_xor(lo, m, 64);
  hi = __shfl_xor(hi, m, 64);
  return (((unsigned long long)hi) << 32) | lo;
}

// ---------------- prep: squared norms + split-fp16 (hi, lo) ----------------
__global__ void prep_x(const float* __restrict__ x, float* __restrict__ sq,
                       unsigned short* __restrict__ xh, unsigned short* __restrict__ xl) {
  int i = blockIdx.x * blockDim.x + threadIdx.x;
  if (i >= NS) return;
  const float4* x4 = (const float4*)(x + (size_t)i * NC);
  float s = 0.f;
#pragma unroll
  for (int k = 0; k < 8; k++) {
    float4 a = x4[2*k], b = x4[2*k+1];
    float f[8] = {a.x,a.y,a.z,a.w,b.x,b.y,b.z,b.w};
    ushort8 hv, lv;
#pragma unroll
    for (int j = 0; j < 8; j++) {
      float v = f[j];
      s += v*v;
      _Float16 h = (_Float16)v;
      float r = v - (float)h;
      _Float16 l = (_Float16)r;
      union { _Float16 ff; unsigned short u; } ch, cl;
      ch.ff = h; cl.ff = l;
      hv[j] = ch.u; lv[j] = cl.u;
    }
    *(ushort8*)(xh + (size_t)i*64 + k*8) = hv;
    *(ushort8*)(xl + (size_t)i*64 + k*8) = lv;
  }
  sq[i] = s;
}

// ---------------- kNN v5b: register MFMA + shared row threshold + cond. stash ----------------
__global__ __launch_bounds__(256) void knn5_kernel(const unsigned short* __restrict__ xh,
                                                   const unsigned short* __restrict__ xl,
                                                   const float* __restrict__ sq,
                                                   int* __restrict__ nbr) {
  __shared__ unsigned short rAh[64*64], rAl[64*64];
  __shared__ unsigned short cBh[64*64], cBl[64*64];
  __shared__ float sqc[64];
  __shared__ float d2s[256*17];
  int b = blockIdx.x >> 5;
  int rb = blockIdx.x & 31;
  int w = threadIdx.x >> 6, lane = threadIdx.x & 63;
  int n16 = lane & 15, q = lane >> 4;
  int rowbase = b*NN + rb*64;
  float* myd2 = &d2s[threadIdx.x * 17];

  {
    int r = threadIdx.x >> 2;
    int c0 = (threadIdx.x & 3) * 2;
#pragma unroll
    for (int cc = 0; cc < 2; cc++) {
      int c = c0 + cc;
      int pos = (c ^ (r & 7)) * 8;
      *(ushort8*)&rAh[r*64 + pos] = *(const ushort8*)(xh + (size_t)(rowbase + r)*64 + c*8);
      *(ushort8*)&rAl[r*64 + pos] = *(const ushort8*)(xl + (size_t)(rowbase + r)*64 + c*8);
    }
  }
  __syncthreads();
  half8 bh[2], bl[2];
  int m = w*16 + n16;
#pragma unroll
  for (int ks = 0; ks < 2; ks++) {
    int pos = ((ks*4 + q) ^ (m & 7)) * 8;
    bh[ks] = *(const half8*)&rAh[m*64 + pos];
    bl[ks] = *(const half8*)&rAl[m*64 + pos];
  }
  float sqr = sq[rowbase + m];

  unsigned long long keys[16];   // sorted ascending; keys[15] = current worst
#pragma unroll
  for (int i = 0; i < 16; i++) keys[i] = ~0ull;
  float wd2 = __builtin_inff();  // row-wide shared threshold (upper bound on final 16th)

  for (int ch = 0; ch < 32; ch++) {
    int colbase = b*NN + ch*64;
    __syncthreads();
    {
      int r = threadIdx.x >> 2;
      int c0 = (threadIdx.x & 3) * 2;
#pragma unroll
      for (int cc = 0; cc < 2; cc++) {
        int c = c0 + cc;
        int pos = (c ^ (r & 7)) * 8;
        *(ushort8*)&cBh[r*64 + pos] = *(const ushort8*)(xh + (size_t)(colbase + r)*64 + c*8);
        *(ushort8*)&cBl[r*64 + pos] = *(const ushort8*)(xl + (size_t)(colbase + r)*64 + c*8);
      }
      if (threadIdx.x < 64) sqc[threadIdx.x] = sq[colbase + threadIdx.x];
    }
    __syncthreads();
    f32x4 acc[4];
#pragma unroll
    for (int ci = 0; ci < 4; ci++) acc[ci] = (f32x4){0.f,0.f,0.f,0.f};
#pragma unroll
    for (int ks = 0; ks < 2; ks++) {
#pragma unroll
      for (int ci = 0; ci < 4; ci++) {
        int n = ci*16 + n16;
        int pos = ((ks*4 + q) ^ (n & 7)) * 8;
        half8 ah_ = *(const half8*)&cBh[n*64 + pos];
        half8 al_ = *(const half8*)&cBl[n*64 + pos];
        acc[ci] = __builtin_amdgcn_mfma_f32_16x16x32_f16(ah_, bh[ks], acc[ci], 0, 0, 0);
        acc[ci] = __builtin_amdgcn_mfma_f32_16x16x32_f16(al_, bh[ks], acc[ci], 0, 0, 0);
        acc[ci] = __builtin_amdgcn_mfma_f32_16x16x32_f16(ah_, bl[ks], acc[ci], 0, 0, 0);
      }
    }
    // filter vs shared row threshold
    float d2v[16];
    unsigned mask = 0;
#pragma unroll
    for (int ci = 0; ci < 4; ci++)
#pragma unroll
      for (int r = 0; r < 4; r++) {
        int idx = ci*4 + r;
        float d2 = fmaf(-2.f, acc[ci][r], sqr + sqc[ci*16 + q*4 + r]);
        d2v[idx] = d2;
        mask |= (d2 <= wd2) ? (1u << idx) : 0u;
      }
    if (mask) {
#pragma unroll
      for (int i = 0; i < 16; i++) myd2[i] = d2v[i];
      while (mask) {
        int i = __builtin_ctz(mask);
        mask &= mask - 1;
        float dd = myd2[i];
        if (dd > wd2) continue;   // stale after earlier inserts this chunk
        int col = colbase + (i >> 2)*16 + q*4 + (i & 3);
        unsigned long long key = ((unsigned long long)orderf(dd) << 32) | (unsigned)col;
#pragma unroll
        for (int j = 0; j < 16; j++) {
          bool cl = key < keys[j];
          unsigned long long lo = cl ? key : keys[j];
          key = cl ? keys[j] : key;
          keys[j] = lo;
        }
        wd2 = fminf(wd2, unorderf((unsigned)(keys[15] >> 32)));
      }
    }
    // chunk end (uniform flow): share min of the 4 quarter-lanes' 16th-best
    {
      unsigned whi = (unsigned)(keys[15] >> 32);
      unsigned o = __shfl_xor(whi, 16, 64); whi = (o < whi) ? o : whi;
      o = __shfl_xor(whi, 32, 64); whi = (o < whi) ? o : whi;
      wd2 = unorderf(whi);
    }
  }
  // merge the 4 col-partition lists per row (lanes n16, +16, +32, +48)
  for (int j = 0; j < NK; j++) {
    unsigned long long mk = keys[0];
#pragma unroll
    for (int i = 1; i < 16; i++) mk = (keys[i] < mk) ? keys[i] : mk;
    unsigned long long o = shfl_xor_u64(mk, 16); mk = (o < mk) ? o : mk;
    o = shfl_xor_u64(mk, 32); mk = (o < mk) ? o : mk;
#pragma unroll
    for (int i = 0; i < 16; i++) if (keys[i] == mk) keys[i] = ~0ull;
    if (q == 0) nbr[(size_t)(rowbase + m)*NK + j] = (int)(mk & 0xffffffffu);
  }
}

// ---------------- weight prep: transpose + bf16, Wt[col][k] ----------------
__global__ void prep_weights(const float* __restrict__ sW1, const float* __restrict__ sW2,
                             const float* __restrict__ tW1, const float* __restrict__ tW2,
                             const float* __restrict__ fW,
                             unsigned short* __restrict__ sW1t, unsigned short* __restrict__ sW2t,
                             unsigned short* __restrict__ tW1t, unsigned short* __restrict__ tW2t,
                             unsigned short* __restrict__ fWt) {
  int i = blockIdx.x * blockDim.x + threadIdx.x;
  if (i < 4*16384) {
    int mi = i >> 14, e = i & 16383;
    int h = e >> 7, k = e & 127;
    const float* src = (mi==0) ? sW1 : (mi==1) ? sW2 : (mi==2) ? tW1 : tW2;
    unsigned short* dst = (mi==0) ? sW1t : (mi==1) ? sW2t : (mi==2) ? tW1t : tW2t;
    dst[h*128 + k] = f2bf(src[k*128 + h]);
  } else {
    int e = i - 4*16384;
    if (e < 128*256) {
      int h = e >> 8, k = e & 255;
      fWt[h*256 + k] = f2bf(fW[k*128 + h]);
    }
  }
}

// ---------------- per-node term: P = bf16(x) @ W1_top (both streams) ----------------
__global__ __launch_bounds__(256) void pnode_kernel(
    const float* __restrict__ x,
    const unsigned short* __restrict__ sW1t, const unsigned short* __restrict__ tW1t,
    float* __restrict__ PS, float* __restrict__ PT) {
  __shared__ unsigned short xt_[64*64];
  int rowbase = blockIdx.x * 64;
  int lane = threadIdx.x & 63;
  int wave = threadIdx.x >> 6;
  int n16 = lane & 15, q = lane >> 4;
  int cb = wave * 32;
  {
    int r = threadIdx.x >> 2, part = threadIdx.x & 3;
    const float4* xp = (const float4*)(x + (size_t)(rowbase + r) * NC) + part*4;
#pragma unroll
    for (int cc = 0; cc < 2; cc++) {
      int c = part*2 + cc;
      float4 a = xp[cc*2], b = xp[cc*2+1];
      int pos = (c ^ (r & 7)) * 8;
      unsigned short* d = &xt_[r*64 + pos];
      d[0]=f2bf(a.x); d[1]=f2bf(a.y); d[2]=f2bf(a.z); d[3]=f2bf(a.w);
      d[4]=f2bf(b.x); d[5]=f2bf(b.y); d[6]=f2bf(b.z); d[7]=f2bf(b.w);
    }
  }
  __syncthreads();
  f32x4 aS[4][2], aT[4][2];
#pragma unroll
  for (int ri = 0; ri < 4; ri++)
#pragma unroll
    for (int ci = 0; ci < 2; ci++) {
      aS[ri][ci] = (f32x4){0.f,0.f,0.f,0.f};
      aT[ri][ci] = (f32x4){0.f,0.f,0.f,0.f};
    }
#pragma unroll
  for (int ks = 0; ks < 2; ks++) {
    short8 af[4];
#pragma unroll
    for (int ri = 0; ri < 4; ri++) {
      int m = ri*16 + n16;
      af[ri] = *(const short8*)&xt_[m*64 + (((ks*4+q) ^ (m & 7)))*8];
    }
#pragma unroll
    for (int ci = 0; ci < 2; ci++) {
      int col = cb + ci*16 + n16;
      short8 bS = *(const short8*)(sW1t + col*128 + (ks*4+q)*8);
      short8 bT = *(const short8*)(tW1t + col*128 + (ks*4+q)*8);
#pragma unroll
      for (int ri = 0; ri < 4; ri++) {
        aS[ri][ci] = __builtin_amdgcn_mfma_f32_16x16x32_bf16(af[ri], bS, aS[ri][ci], 0, 0, 0);
        aT[ri][ci] = __builtin_amdgcn_mfma_f32_16x16x32_bf16(af[ri], bT, aT[ri][ci], 0, 0, 0);
      }
    }
  }
#pragma unroll
  for (int ri = 0; ri < 4; ri++)
#pragma unroll
    for (int ci = 0; ci < 2; ci++) {
      int col = cb + ci*16 + n16;
#pragma unroll
      for (int r = 0; r < 4; r++) {
        int row = rowbase + ri*16 + q*4 + r;
        PS[(size_t)row*128 + col] = aS[ri][ci][r];
        PT[(size_t)row*128 + col] = aT[ri][ci][r];
      }
    }
}

// ---------------- fused D-build + MODE0 stats (sequential streams, 4 wg/CU) ----------------
__global__ __launch_bounds__(256, 4) void dstat_kernel(
    const float* __restrict__ x, const int* __restrict__ nbr,
    const unsigned short* __restrict__ sW1t, const unsigned short* __restrict__ tW1t,
    const float* __restrict__ PS, const float* __restrict__ PT,
    unsigned short* __restrict__ D,
    float* __restrict__ statS, float* __restrict__ statT) {
  __shared__ unsigned short dlds[64*64];
  int wave = threadIdx.x >> 6, lane = threadIdx.x & 63;
  int n16 = lane & 15, q = lane >> 4;
  int cb = wave * 32;
  int g = blockIdx.x & 15, sub = blockIdx.x >> 4;   // graph pinned to XCD g%8
  float psS[2]={0,0}, ps2S[2]={0,0}, psT[2]={0,0}, ps2T[2]={0,0};

  for (int it = 0; it < 4; it++) {
    int tile = g*512 + sub*4 + it;
    __syncthreads();
    {
      int r4 = threadIdx.x >> 2, part = threadIdx.x & 3;
      int s = tile*64 + r4;
      int node = s >> 4;
      int ng = nbr[s];
      const float4* xi = (const float4*)(x + (size_t)node * NC) + part*4;
      const float4* xj = (const float4*)(x + (size_t)ng  * NC) + part*4;
      unsigned short* dstg = D + (size_t)tile*4096 + (size_t)r4*64;
#pragma unroll
      for (int cc = 0; cc < 2; cc++) {
        int c = part*2 + cc;
        float4 a0 = xi[cc*2], a1 = xi[cc*2+1];
        float4 b0 = xj[cc*2], b1 = xj[cc*2+1];
        int pos = (c ^ (r4 & 7)) * 8;
        ushort8 dv;
        dv[0]=f2bf(b0.x-a0.x); dv[1]=f2bf(b0.y-a0.y); dv[2]=f2bf(b0.z-a0.z); dv[3]=f2bf(b0.w-a0.w);
        dv[4]=f2bf(b1.x-a1.x); dv[5]=f2bf(b1.y-a1.y); dv[6]=f2bf(b1.z-a1.z); dv[7]=f2bf(b1.w-a1.w);
        *(ushort8*)(dstg + pos) = dv;
        *(ushort8*)(dlds + r4*64 + pos) = dv;
      }
    }
    __syncthreads();
    int node0 = tile*4;
#pragma unroll
    for (int st = 0; st < 2; st++) {
      const unsigned short* W1t = st ? tW1t : sW1t;
      const float* P = st ? PT : PS;
      float* ps  = st ? psT : psS;
      float* ps2 = st ? ps2T : ps2S;
      float pp[4][2];
#pragma unroll
      for (int ri = 0; ri < 4; ri++)
#pragma unroll
        for (int ci = 0; ci < 2; ci++)
          pp[ri][ci] = P[(size_t)(node0+ri)*128 + cb + ci*16 + n16];
      f32x4 a[4][2];
#pragma unroll
      for (int ri = 0; ri < 4; ri++)
#pragma unroll
        for (int ci = 0; ci < 2; ci++)
          a[ri][ci] = (f32x4){0.f,0.f,0.f,0.f};
#pragma unroll
      for (int ks = 0; ks < 2; ks++) {
        short8 af[4];
#pragma unroll
        for (int ri = 0; ri < 4; ri++) {
          int mm = ri*16 + n16;
          af[ri] = *(const short8*)&dlds[mm*64 + ((ks*4+q) ^ (mm & 7))*8];
        }
#pragma unroll
        for (int ci = 0; ci < 2; ci++) {
          int col = cb + ci*16 + n16;
          short8 bf = *(const short8*)(W1t + col*128 + 64 + (ks*4+q)*8);
#pragma unroll
          for (int ri = 0; ri < 4; ri++)
            a[ri][ci] = __builtin_amdgcn_mfma_f32_16x16x32_bf16(af[ri], bf, a[ri][ci], 0, 0, 0);
        }
      }
#pragma unroll
      for (int ci = 0; ci < 2; ci++)
#pragma unroll
        for (int ri = 0; ri < 4; ri++)
#pragma unroll
          for (int r = 0; r < 4; r++) {
            float v = a[ri][ci][r] + pp[ri][ci];
            ps[ci] += v; ps2[ci] += v*v;
          }
    }
  }
#pragma unroll
  for (int ci = 0; ci < 2; ci++) {
    int col = cb + ci*16 + n16;
    float a = psS[ci], a2 = ps2S[ci], b2v = psT[ci], b3 = ps2T[ci];
    a   += __shfl_xor(a, 16, 64);   a   += __shfl_xor(a, 32, 64);
    a2  += __shfl_xor(a2, 16, 64);  a2  += __shfl_xor(a2, 32, 64);
    b2v += __shfl_xor(b2v, 16, 64); b2v += __shfl_xor(b2v, 32, 64);
    b3  += __shfl_xor(b3, 16, 64);  b3  += __shfl_xor(b3, 32, 64);
    if (q == 0) {
      atomicAdd(&statS[col], a);
      atomicAdd(&statS[128 + col], a2);
      atomicAdd(&statT[col], b2v);
      atomicAdd(&statT[128 + col], b3);
    }
  }
}

// ---------------- BN passes over D + P ----------------
// MODE 1: h1 -> bn1+relu -> GEMM2 -> stats2
// MODE 2: -> bn2+relu -> max over K -> [xs|xt] in LDS -> @f_W -> gout + statF
template<int MODE>
__global__ __launch_bounds__(256, 4) void mlp_pass2(
    const unsigned short* __restrict__ D,
    const float* __restrict__ PS, const float* __restrict__ PT,
    const unsigned short* __restrict__ sW1t, const unsigned short* __restrict__ sW2t,
    const unsigned short* __restrict__ tW1t, const unsigned short* __restrict__ tW2t,
    const unsigned short* __restrict__ fWt,
    const float* __restrict__ affS1, const float* __restrict__ affS2,
    const float* __restrict__ affT1, const float* __restrict__ affT2,
    float* __restrict__ statS, float* __restrict__ statT,
    float* __restrict__ statF, float* __restrict__ gout) {
  __shared__ unsigned short dlds[64*64];
  __shared__ unsigned short atile[64*128];
  __shared__ unsigned short xtile[(MODE == 2) ? 16*256 : 64];
  int wave = threadIdx.x >> 6;
  int lane = threadIdx.x & 63;
  int n16 = lane & 15, q = lane >> 4;
  int cb = wave * 32;

  float s1S[2], h1S[2], s2S[2], h2S[2];
  float s1T[2], h1T[2], s2T[2], h2T[2];
#pragma unroll
  for (int ci = 0; ci < 2; ci++) {
    int col = cb + ci*16 + n16;
    s1S[ci] = affS1[col]; h1S[ci] = affS1[128 + col];
    s1T[ci] = affT1[col]; h1T[ci] = affT1[128 + col];
  }
  if (MODE == 2) {
#pragma unroll
    for (int ci = 0; ci < 2; ci++) {
      int col = cb + ci*16 + n16;
      s2S[ci] = affS2[col]; h2S[ci] = affS2[128 + col];
      s2T[ci] = affT2[col]; h2T[ci] = affT2[128 + col];
    }
  }
  float psS[2] = {0,0}, ps2S[2] = {0,0};
  float psT[2] = {0,0}, ps2T[2] = {0,0};

  for (int it = 0; it < 4; it++) {
    int tile = blockIdx.x*4 + it;
    __syncthreads();
    {
      const ushort8* src = (const ushort8*)(D + (size_t)tile*4096);
      ushort8* dst = (ushort8*)dlds;
      dst[threadIdx.x] = src[threadIdx.x];
      dst[threadIdx.x + 256] = src[threadIdx.x + 256];
    }
    __syncthreads();
    int node0 = tile*4;
    float pS[4][2], pT[4][2];
#pragma unroll
    for (int ri = 0; ri < 4; ri++)
#pragma unroll
      for (int ci = 0; ci < 2; ci++) {
        int col = cb + ci*16 + n16;
        pS[ri][ci] = PS[(size_t)(node0+ri)*128 + col];
        pT[ri][ci] = PT[(size_t)(node0+ri)*128 + col];
      }

#pragma unroll
    for (int st = 0; st < 2; st++) {
      const unsigned short* W1t = st ? tW1t : sW1t;
      const unsigned short* W2t = st ? tW2t : sW2t;
      const float* sc1 = st ? s1T : s1S;  const float* sh1 = st ? h1T : h1S;
      const float* sc2 = st ? s2T : s2S;  const float* sh2 = st ? h2T : h2S;
      float (*pp)[2] = st ? pT : pS;
      float* ps  = st ? psT : psS;
      float* ps2 = st ? ps2T : ps2S;

      // GEMM1 (bottom half, K=64): h1 = P + D @ W1bot
      f32x4 acc[4][2];
#pragma unroll
      for (int ri = 0; ri < 4; ri++)
#pragma unroll
        for (int ci = 0; ci < 2; ci++)
          acc[ri][ci] = (f32x4){0.f,0.f,0.f,0.f};
#pragma unroll
      for (int ks = 0; ks < 2; ks++) {
        short8 af[4], bf[2];
#pragma unroll
        for (int ri = 0; ri < 4; ri++) {
          int mm = ri*16 + n16;
          af[ri] = *(const short8*)&dlds[mm*64 + ((ks*4+q) ^ (mm & 7))*8];
        }
#pragma unroll
        for (int ci = 0; ci < 2; ci++) {
          int col = cb + ci*16 + n16;
          bf[ci] = *(const short8*)(W1t + col*128 + 64 + (ks*4+q)*8);
        }
#pragma unroll
        for (int ri = 0; ri < 4; ri++)
#pragma unroll
          for (int ci = 0; ci < 2; ci++)
            acc[ri][ci] = __builtin_amdgcn_mfma_f32_16x16x32_bf16(af[ri], bf[ci], acc[ri][ci], 0, 0, 0);
      }
      // bn1 + relu -> a-tile (bf16, swizzled)
#pragma unroll
      for (int ri = 0; ri < 4; ri++)
#pragma unroll
        for (int ci = 0; ci < 2; ci++) {
          int colL = cb + ci*16 + n16;
          int kc8 = colL >> 3;
#pragma unroll
          for (int r = 0; r < 4; r++) {
            float v = acc[ri][ci][r] + pp[ri][ci];
            v = fmaxf(v * sc1[ci] + sh1[ci], 0.f);
            int rowL = ri*16 + q*4 + r;
            int pos = ((kc8 ^ (rowL & 7)) << 3) + (colL & 7);
            atile[rowL*128 + pos] = f2bf(v);
          }
        }
      __syncthreads();
      // GEMM2 (K=128)
      f32x4 acc2[4][2];
#pragma unroll
      for (int ri = 0; ri < 4; ri++)
#pragma unroll
        for (int ci = 0; ci < 2; ci++)
          acc2[ri][ci] = (f32x4){0.f,0.f,0.f,0.f};
#pragma unroll
      for (int ks = 0; ks < 4; ks++) {
        short8 a2[4], bf[2];
#pragma unroll
        for (int ri = 0; ri < 4; ri++) {
          int mm = ri*16 + n16;
          int kc8 = (ks*4 + q) ^ (mm & 7);
          a2[ri] = *(const short8*)&atile[mm*128 + kc8*8];
        }
#pragma unroll
        for (int ci = 0; ci < 2; ci++) {
          int col = cb + ci*16 + n16;
          bf[ci] = *(const short8*)(W2t + col*128 + ks*32 + q*8);
        }
#pragma unroll
        for (int ri = 0; ri < 4; ri++)
#pragma unroll
          for (int ci = 0; ci < 2; ci++)
            acc2[ri][ci] = __builtin_amdgcn_mfma_f32_16x16x32_bf16(a2[ri], bf[ci], acc2[ri][ci], 0, 0, 0);
      }
      if (MODE == 1) {
#pragma unroll
        for (int ci = 0; ci < 2; ci++)
#pragma unroll
          for (int ri = 0; ri < 4; ri++)
#pragma unroll
            for (int r = 0; r < 4; r++) {
              float v = acc2[ri][ci][r];
              ps[ci] += v; ps2[ci] += v*v;
            }
      } else {
        // bn2+relu+max over K -> xtile (16 nodes x 256 ch, swizzled for final GEMM)
#pragma unroll
        for (int ri = 0; ri < 4; ri++)
#pragma unroll
          for (int ci = 0; ci < 2; ci++) {
            int col = cb + ci*16 + n16;
            float vm = 0.f;
#pragma unroll
            for (int r = 0; r < 4; r++) {
              float v = fmaxf(acc2[ri][ci][r] * sc2[ci] + sh2[ci], 0.f);
              vm = fmaxf(vm, v);
            }
            vm = fmaxf(vm, __shfl_xor(vm, 16, 64));
            vm = fmaxf(vm, __shfl_xor(vm, 32, 64));
            if (q == 0) {
              int ln = it*4 + ri;               // local node 0..15
              int fcol = st*128 + col;          // 0..255
              int kc8 = fcol >> 3;
              int pos = ((kc8 ^ (ln & 7)) << 3) + (fcol & 7);
              xtile[ln*256 + pos] = f2bf(vm);
            }
          }
      }
      if (st == 0) __syncthreads();
    }
  }
  if (MODE == 1) {
#pragma unroll
    for (int ci = 0; ci < 2; ci++) {
      int col = cb + ci*16 + n16;
      float a = psS[ci], a2 = ps2S[ci], b = psT[ci], b2 = ps2T[ci];
      a  += __shfl_xor(a, 16, 64);  a  += __shfl_xor(a, 32, 64);
      a2 += __shfl_xor(a2, 16, 64); a2 += __shfl_xor(a2, 32, 64);
      b  += __shfl_xor(b, 16, 64);  b  += __shfl_xor(b, 32, 64);
      b2 += __shfl_xor(b2, 16, 64); b2 += __shfl_xor(b2, 32, 64);
      if (q == 0) {
        atomicAdd(&statS[col], a);
        atomicAdd(&statS[128 + col], a2);
        atomicAdd(&statT[col], b);
        atomicAdd(&statT[128 + col], b2);
      }
    }
  } else {
    // fused final linear: gout = [xs|xt] @ f_W (16 nodes), + statF
    __syncthreads();
    f32x4 facc[2];
#pragma unroll
    for (int ci = 0; ci < 2; ci++) facc[ci] = (f32x4){0.f,0.f,0.f,0.f};
#pragma unroll
    for (int ks = 0; ks < 8; ks++) {
      int kc8 = (ks*4 + q) ^ (n16 & 7);
      short8 af = *(const short8*)&xtile[n16*256 + kc8*8];
#pragma unroll
      for (int ci = 0; ci < 2; ci++) {
        int col = cb + ci*16 + n16;
        short8 bf = *(const short8*)(fWt + col*256 + ks*32 + q*8);
        facc[ci] = __builtin_amdgcn_mfma_f32_16x16x32_bf16(af, bf, facc[ci], 0, 0, 0);
      }
    }
    int nodeBase = blockIdx.x * 16;
    float fs[2] = {0,0}, fs2[2] = {0,0};
#pragma unroll
    for (int ci = 0; ci < 2; ci++) {
      int col = cb + ci*16 + n16;
#pragma unroll
      for (int r = 0; r < 4; r++) {
        float v = facc[ci][r];
        gout[(size_t)(nodeBase + q*4 + r)*128 + col] = v;
        fs[ci] += v; fs2[ci] += v*v;
      }
      float a = fs[ci], a2 = fs2[ci];
      a  += __shfl_xor(a, 16, 64);  a  += __shfl_xor(a, 32, 64);
      a2 += __shfl_xor(a2, 16, 64); a2 += __shfl_xor(a2, 32, 64);
      if (q == 0) {
        atomicAdd(&statF[col], a);
        atomicAdd(&statF[128 + col], a2);
      }
    }
  }
}

// ---------------- finalize BN stats -> (scale, shift) ----------------
__global__ void finalize_kernel(const float* __restrict__ stats,
                                const float* __restrict__ g,
                                const float* __restrict__ be,
                                float* __restrict__ aff, float invcount) {
  int c = threadIdx.x;
  if (c < 128) {
    float mean = stats[c] * invcount;
    float var = stats[128 + c] * invcount - mean*mean;
    float scale = g[c] / sqrtf(var + EPSV);
    aff[c] = scale;
    aff[128 + c] = be[c] - mean * scale;
  }
}

__global__ void apply_bn_kernel(float* __restrict__ out, const float* __restrict__ aff) {
  int i = blockIdx.x * blockDim.x + threadIdx.x;
  if (i < NS*NH) {
    int c = i & 127;
    out[i] = fmaxf(out[i] * aff[c] + aff[128 + c], 0.f);
  }
}

extern "C" void kernel_launch(void* const* d_in, const int* in_sizes, int n_in,
                              void* d_out, int out_size, void* d_ws, size_t ws_size,
                              hipStream_t stream) {
  const float* x   = (const float*)d_in[0];
  const float* sW1 = (const float*)d_in[2];
  const float* sg1 = (const float*)d_in[4];
  const float* sbe1= (const float*)d_in[5];
  const float* sW2 = (const float*)d_in[6];
  const float* sg2 = (const float*)d_in[8];
  const float* sbe2= (const float*)d_in[9];
  const float* tW1 = (const float*)d_in[10];
  const float* tg1 = (const float*)d_in[12];
  const float* tbe1= (const float*)d_in[13];
  const float* tW2 = (const float*)d_in[14];
  const float* tg2 = (const float*)d_in[16];
  const float* tbe2= (const float*)d_in[17];
  const float* fW  = (const float*)d_in[18];
  const float* fg  = (const float*)d_in[20];
  const float* fbe = (const float*)d_in[21];
  float* out = (float*)d_out;

  char* w = (char*)d_ws;
  float* sq = (float*)w;                 w += (size_t)NS*4;
  int* nbr = (int*)w;                    w += (size_t)NSK*4;
  unsigned short* sW1t = (unsigned short*)w; w += 32768;
  unsigned short* sW2t = (unsigned short*)w; w += 32768;
  unsigned short* tW1t = (unsigned short*)w; w += 32768;
  unsigned short* tW2t = (unsigned short*)w; w += 32768;
  unsigned short* fWt  = (unsigned short*)w; w += 65536;
  float* stats = (float*)w;              w += 2560*4;
  unsigned short* xh = (unsigned short*)w; w += (size_t)NS*64*2;
  unsigned short* xl = (unsigned short*)w; w += (size_t)NS*64*2;
  unsigned short* Dg = (unsigned short*)w; w += (size_t)NSK*64*2;
  float* PS = (float*)w;                 w += (size_t)NS*128*4;
  float* PT = (float*)w;                 w += (size_t)NS*128*4;

  float* st_s1 = stats;        float* af_s1 = stats + 256;
  float* st_s2 = stats + 512;  float* af_s2 = stats + 768;
  float* st_t1 = stats + 1024; float* af_t1 = stats + 1280;
  float* st_t2 = stats + 1536; float* af_t2 = stats + 1792;
  float* st_f  = stats + 2048; float* af_f  = stats + 2304;

  hipMemsetAsync(stats, 0, 2560*4, stream);
  prep_weights<<<(4*16384 + 128*256 + 255)/256, 256, 0, stream>>>(
      sW1, sW2, tW1, tW2, fW, sW1t, sW2t, tW1t, tW2t, fWt);
  prep_x<<<NS/256, 256, 0, stream>>>(x, sq, xh, xl);
  knn5_kernel<<<NB*32, 256, 0, stream>>>(xh, xl, sq, nbr);
  pnode_kernel<<<NS/64, 256, 0, stream>>>(x, sW1t, tW1t, PS, PT);
  dstat_kernel<<<2048, 256, 0, stream>>>(x, nbr, sW1t, tW1t, PS, PT, Dg, st_s1, st_t1);

  const float inv1 = 1.f/(float)NSK, invf = 1.f/(float)NS;
  finalize_kernel<<<1,128,0,stream>>>(st_s1, sg1, sbe1, af_s1, inv1);
  finalize_kernel<<<1,128,0,stream>>>(st_t1, tg1, tbe1, af_t1, inv1);
  mlp_pass2<1><<<2048,256,0,stream>>>(Dg, PS, PT, sW1t, sW2t, tW1t, tW2t, fWt,
      af_s1, nullptr, af_t1, nullptr, st_s2, st_t2, nullptr, nullptr);
  finalize_kernel<<<1,128,0,stream>>>(st_s2, sg2, sbe2, af_s2, inv1);
  finalize_kernel<<<1,128,0,stream>>>(st_t2, tg2, tbe2, af_t2, inv1);
  mlp_pass2<2><<<2048,256,0,stream>>>(Dg, PS, PT, sW1t, sW2t, tW1t, tW2t, fWt,
      af_s1, af_s2, af_t1, af_t2, nullptr, nullptr, st_f, out);
  finalize_kernel<<<1,128,0,stream>>>(st_f, fg, fbe, af_f, invf);
  apply_bn_kernel<<<(NS*NH)/256, 256, 0, stream>>>(out, af_f);
}

// Round 10
// 564.508 us; speedup vs baseline: 1.5408x; 1.5408x over previous
//
#include <hip/hip_runtime.h>
#include <hip/hip_bf16.h>
#include <stdint.h>

#define NB 16
#define NN 2048
#define NC 64
#define NH 128
#define NK 16
#define NS (NB*NN)
#define NSK (NS*NK)
#define EPSV 1e-5f

typedef __attribute__((ext_vector_type(8))) short short8;
typedef __attribute__((ext_vector_type(8))) _Float16 half8;
typedef __attribute__((ext_vector_type(8))) unsigned short ushort8;
typedef __attribute__((ext_vector_type(4))) float f32x4;

__device__ __forceinline__ unsigned short f2bf(float x) {
  union { float f; unsigned u; } v; v.f = x;
  unsigned r = v.u + 0x7fffu + ((v.u >> 16) & 1u);
  return (unsigned short)(r >> 16);
}

__device__ __forceinline__ unsigned orderf(float f) {
  unsigned u = __float_as_uint(f);
  return u ^ ((unsigned)((int)u >> 31) | 0x80000000u);
}

__device__ __forceinline__ float unorderf(unsigned whi) {
  return (whi == 0xffffffffu) ? __builtin_inff()
       : __uint_as_float((whi & 0x80000000u) ? (whi ^ 0x80000000u) : ~whi);
}

__device__ __forceinline__ unsigned long long shfl_xor_u64(unsigned long long v, int m) {
  unsigned lo = (unsigned)(v & 0xffffffffull);
  unsigned hi = (unsigned)(v >> 32);
  lo = __shfl_xor(lo, m, 64);
  hi = __shfl_xor(hi, m, 64);
  return (((unsigned long long)hi) << 32) | lo;
}

// ---------------- prep: squared norms + split-fp16 (hi, lo) ----------------
__global__ void prep_x(const float* __restrict__ x, float* __restrict__ sq,
                       unsigned short* __restrict__ xh, unsigned short* __restrict__ xl) {
  int i = blockIdx.x * blockDim.x + threadIdx.x;
  if (i >= NS) return;
  const float4* x4 = (const float4*)(x + (size_t)i * NC);
  float s = 0.f;
#pragma unroll
  for (int k = 0; k < 8; k++) {
    float4 a = x4[2*k], b = x4[2*k+1];
    float f[8] = {a.x,a.y,a.z,a.w,b.x,b.y,b.z,b.w};
    ushort8 hv, lv;
#pragma unroll
    for (int j = 0; j < 8; j++) {
      float v = f[j];
      s += v*v;
      _Float16 h = (_Float16)v;
      float r = v - (float)h;
      _Float16 l = (_Float16)r;
      union { _Float16 ff; unsigned short u; } ch, cl;
      ch.ff = h; cl.ff = l;
      hv[j] = ch.u; lv[j] = cl.u;
    }
    *(ushort8*)(xh + (size_t)i*64 + k*8) = hv;
    *(ushort8*)(xl + (size_t)i*64 + k*8) = lv;
  }
  sq[i] = s;
}

// ---------------- kNN v5b: register MFMA + shared row threshold + cond. stash ----------------
__global__ __launch_bounds__(256) void knn5_kernel(const unsigned short* __restrict__ xh,
                                                   const unsigned short* __restrict__ xl,
                                                   const float* __restrict__ sq,
                                                   int* __restrict__ nbr) {
  __shared__ unsigned short rAh[64*64], rAl[64*64];
  __shared__ unsigned short cBh[64*64], cBl[64*64];
  __shared__ float sqc[64];
  __shared__ float d2s[256*17];
  int b = blockIdx.x >> 5;
  int rb = blockIdx.x & 31;
  int w = threadIdx.x >> 6, lane = threadIdx.x & 63;
  int n16 = lane & 15, q = lane >> 4;
  int rowbase = b*NN + rb*64;
  float* myd2 = &d2s[threadIdx.x * 17];

  {
    int r = threadIdx.x >> 2;
    int c0 = (threadIdx.x & 3) * 2;
#pragma unroll
    for (int cc = 0; cc < 2; cc++) {
      int c = c0 + cc;
      int pos = (c ^ (r & 7)) * 8;
      *(ushort8*)&rAh[r*64 + pos] = *(const ushort8*)(xh + (size_t)(rowbase + r)*64 + c*8);
      *(ushort8*)&rAl[r*64 + pos] = *(const ushort8*)(xl + (size_t)(rowbase + r)*64 + c*8);
    }
  }
  __syncthreads();
  half8 bh[2], bl[2];
  int m = w*16 + n16;
#pragma unroll
  for (int ks = 0; ks < 2; ks++) {
    int pos = ((ks*4 + q) ^ (m & 7)) * 8;
    bh[ks] = *(const half8*)&rAh[m*64 + pos];
    bl[ks] = *(const half8*)&rAl[m*64 + pos];
  }
  float sqr = sq[rowbase + m];

  unsigned long long keys[16];   // sorted ascending; keys[15] = current worst
#pragma unroll
  for (int i = 0; i < 16; i++) keys[i] = ~0ull;
  float wd2 = __builtin_inff();  // row-wide shared threshold

  for (int ch = 0; ch < 32; ch++) {
    int colbase = b*NN + ch*64;
    __syncthreads();
    {
      int r = threadIdx.x >> 2;
      int c0 = (threadIdx.x & 3) * 2;
#pragma unroll
      for (int cc = 0; cc < 2; cc++) {
        int c = c0 + cc;
        int pos = (c ^ (r & 7)) * 8;
        *(ushort8*)&cBh[r*64 + pos] = *(const ushort8*)(xh + (size_t)(colbase + r)*64 + c*8);
        *(ushort8*)&cBl[r*64 + pos] = *(const ushort8*)(xl + (size_t)(colbase + r)*64 + c*8);
      }
      if (threadIdx.x < 64) sqc[threadIdx.x] = sq[colbase + threadIdx.x];
    }
    __syncthreads();
    f32x4 acc[4];
#pragma unroll
    for (int ci = 0; ci < 4; ci++) acc[ci] = (f32x4){0.f,0.f,0.f,0.f};
#pragma unroll
    for (int ks = 0; ks < 2; ks++) {
#pragma unroll
      for (int ci = 0; ci < 4; ci++) {
        int n = ci*16 + n16;
        int pos = ((ks*4 + q) ^ (n & 7)) * 8;
        half8 ah_ = *(const half8*)&cBh[n*64 + pos];
        half8 al_ = *(const half8*)&cBl[n*64 + pos];
        acc[ci] = __builtin_amdgcn_mfma_f32_16x16x32_f16(ah_, bh[ks], acc[ci], 0, 0, 0);
        acc[ci] = __builtin_amdgcn_mfma_f32_16x16x32_f16(al_, bh[ks], acc[ci], 0, 0, 0);
        acc[ci] = __builtin_amdgcn_mfma_f32_16x16x32_f16(ah_, bl[ks], acc[ci], 0, 0, 0);
      }
    }
    float d2v[16];
    unsigned mask = 0;
#pragma unroll
    for (int ci = 0; ci < 4; ci++)
#pragma unroll
      for (int r = 0; r < 4; r++) {
        int idx = ci*4 + r;
        float d2 = fmaf(-2.f, acc[ci][r], sqr + sqc[ci*16 + q*4 + r]);
        d2v[idx] = d2;
        mask |= (d2 <= wd2) ? (1u << idx) : 0u;
      }
    if (mask) {
#pragma unroll
      for (int i = 0; i < 16; i++) myd2[i] = d2v[i];
      while (mask) {
        int i = __builtin_ctz(mask);
        mask &= mask - 1;
        float dd = myd2[i];
        if (dd > wd2) continue;
        int col = colbase + (i >> 2)*16 + q*4 + (i & 3);
        unsigned long long key = ((unsigned long long)orderf(dd) << 32) | (unsigned)col;
#pragma unroll
        for (int j = 0; j < 16; j++) {
          bool cl = key < keys[j];
          unsigned long long lo = cl ? key : keys[j];
          key = cl ? keys[j] : key;
          keys[j] = lo;
        }
        wd2 = fminf(wd2, unorderf((unsigned)(keys[15] >> 32)));
      }
    }
    // share min of the 4 quarter-lanes' 16th-best as row-wide threshold
    {
      unsigned whi = (unsigned)(keys[15] >> 32);
      unsigned o = __shfl_xor(whi, 16, 64); whi = (o < whi) ? o : whi;
      o = __shfl_xor(whi, 32, 64); whi = (o < whi) ? o : whi;
      wd2 = unorderf(whi);
    }
  }
  for (int j = 0; j < NK; j++) {
    unsigned long long mk = keys[0];
#pragma unroll
    for (int i = 1; i < 16; i++) mk = (keys[i] < mk) ? keys[i] : mk;
    unsigned long long o = shfl_xor_u64(mk, 16); mk = (o < mk) ? o : mk;
    o = shfl_xor_u64(mk, 32); mk = (o < mk) ? o : mk;
#pragma unroll
    for (int i = 0; i < 16; i++) if (keys[i] == mk) keys[i] = ~0ull;
    if (q == 0) nbr[(size_t)(rowbase + m)*NK + j] = (int)(mk & 0xffffffffu);
  }
}

// ---------------- weight prep: transpose + bf16, Wt[col][k] ----------------
__global__ void prep_weights(const float* __restrict__ sW1, const float* __restrict__ sW2,
                             const float* __restrict__ tW1, const float* __restrict__ tW2,
                             const float* __restrict__ fW,
                             unsigned short* __restrict__ sW1t, unsigned short* __restrict__ sW2t,
                             unsigned short* __restrict__ tW1t, unsigned short* __restrict__ tW2t,
                             unsigned short* __restrict__ fWt) {
  int i = blockIdx.x * blockDim.x + threadIdx.x;
  if (i < 4*16384) {
    int mi = i >> 14, e = i & 16383;
    int h = e >> 7, k = e & 127;
    const float* src = (mi==0) ? sW1 : (mi==1) ? sW2 : (mi==2) ? tW1 : tW2;
    unsigned short* dst = (mi==0) ? sW1t : (mi==1) ? sW2t : (mi==2) ? tW1t : tW2t;
    dst[h*128 + k] = f2bf(src[k*128 + h]);
  } else {
    int e = i - 4*16384;
    if (e < 128*256) {
      int h = e >> 8, k = e & 255;
      fWt[h*256 + k] = f2bf(fW[k*128 + h]);
    }
  }
}

// ---------------- per-node term: P = bf16(x) @ W1_top (both streams) ----------------
__global__ __launch_bounds__(256) void pnode_kernel(
    const float* __restrict__ x,
    const unsigned short* __restrict__ sW1t, const unsigned short* __restrict__ tW1t,
    float* __restrict__ PS, float* __restrict__ PT) {
  __shared__ unsigned short xt_[64*64];
  int rowbase = blockIdx.x * 64;
  int lane = threadIdx.x & 63;
  int wave = threadIdx.x >> 6;
  int n16 = lane & 15, q = lane >> 4;
  int cb = wave * 32;
  {
    int r = threadIdx.x >> 2, part = threadIdx.x & 3;
    const float4* xp = (const float4*)(x + (size_t)(rowbase + r) * NC) + part*4;
#pragma unroll
    for (int cc = 0; cc < 2; cc++) {
      int c = part*2 + cc;
      float4 a = xp[cc*2], b = xp[cc*2+1];
      int pos = (c ^ (r & 7)) * 8;
      unsigned short* d = &xt_[r*64 + pos];
      d[0]=f2bf(a.x); d[1]=f2bf(a.y); d[2]=f2bf(a.z); d[3]=f2bf(a.w);
      d[4]=f2bf(b.x); d[5]=f2bf(b.y); d[6]=f2bf(b.z); d[7]=f2bf(b.w);
    }
  }
  __syncthreads();
  f32x4 aS[4][2], aT[4][2];
#pragma unroll
  for (int ri = 0; ri < 4; ri++)
#pragma unroll
    for (int ci = 0; ci < 2; ci++) {
      aS[ri][ci] = (f32x4){0.f,0.f,0.f,0.f};
      aT[ri][ci] = (f32x4){0.f,0.f,0.f,0.f};
    }
#pragma unroll
  for (int ks = 0; ks < 2; ks++) {
    short8 af[4];
#pragma unroll
    for (int ri = 0; ri < 4; ri++) {
      int m = ri*16 + n16;
      af[ri] = *(const short8*)&xt_[m*64 + (((ks*4+q) ^ (m & 7)))*8];
    }
#pragma unroll
    for (int ci = 0; ci < 2; ci++) {
      int col = cb + ci*16 + n16;
      short8 bS = *(const short8*)(sW1t + col*128 + (ks*4+q)*8);
      short8 bT = *(const short8*)(tW1t + col*128 + (ks*4+q)*8);
#pragma unroll
      for (int ri = 0; ri < 4; ri++) {
        aS[ri][ci] = __builtin_amdgcn_mfma_f32_16x16x32_bf16(af[ri], bS, aS[ri][ci], 0, 0, 0);
        aT[ri][ci] = __builtin_amdgcn_mfma_f32_16x16x32_bf16(af[ri], bT, aT[ri][ci], 0, 0, 0);
      }
    }
  }
#pragma unroll
  for (int ri = 0; ri < 4; ri++)
#pragma unroll
    for (int ci = 0; ci < 2; ci++) {
      int col = cb + ci*16 + n16;
#pragma unroll
      for (int r = 0; r < 4; r++) {
        int row = rowbase + ri*16 + q*4 + r;
        PS[(size_t)row*128 + col] = aS[ri][ci][r];
        PT[(size_t)row*128 + col] = aT[ri][ci][r];
      }
    }
}

// ---------------- fused D-build + MODE0 stats (round-7 config: 256,2, dual-stream) ----------------
__global__ __launch_bounds__(256, 2) void dstat_kernel(
    const float* __restrict__ x, const int* __restrict__ nbr,
    const unsigned short* __restrict__ sW1t, const unsigned short* __restrict__ tW1t,
    const float* __restrict__ PS, const float* __restrict__ PT,
    unsigned short* __restrict__ D,
    float* __restrict__ statS, float* __restrict__ statT) {
  __shared__ unsigned short dlds[64*64];
  int wave = threadIdx.x >> 6, lane = threadIdx.x & 63;
  int n16 = lane & 15, q = lane >> 4;
  int cb = wave * 32;
  int g = blockIdx.x & 15, sub = blockIdx.x >> 4;   // graph pinned to XCD g%8
  float psS[2]={0,0}, ps2S[2]={0,0}, psT[2]={0,0}, ps2T[2]={0,0};

  for (int it = 0; it < 4; it++) {
    int tile = g*512 + sub*4 + it;
    __syncthreads();
    {
      int r4 = threadIdx.x >> 2, part = threadIdx.x & 3;
      int s = tile*64 + r4;
      int node = s >> 4;
      int ng = nbr[s];
      const float4* xi = (const float4*)(x + (size_t)node * NC) + part*4;
      const float4* xj = (const float4*)(x + (size_t)ng  * NC) + part*4;
      unsigned short* dstg = D + (size_t)tile*4096 + (size_t)r4*64;
#pragma unroll
      for (int cc = 0; cc < 2; cc++) {
        int c = part*2 + cc;
        float4 a0 = xi[cc*2], a1 = xi[cc*2+1];
        float4 b0 = xj[cc*2], b1 = xj[cc*2+1];
        int pos = (c ^ (r4 & 7)) * 8;
        ushort8 dv;
        dv[0]=f2bf(b0.x-a0.x); dv[1]=f2bf(b0.y-a0.y); dv[2]=f2bf(b0.z-a0.z); dv[3]=f2bf(b0.w-a0.w);
        dv[4]=f2bf(b1.x-a1.x); dv[5]=f2bf(b1.y-a1.y); dv[6]=f2bf(b1.z-a1.z); dv[7]=f2bf(b1.w-a1.w);
        *(ushort8*)(dstg + pos) = dv;
        *(ushort8*)(dlds + r4*64 + pos) = dv;
      }
    }
    __syncthreads();
    int node0 = tile*4;
    float pS[4][2], pT[4][2];
#pragma unroll
    for (int ri = 0; ri < 4; ri++)
#pragma unroll
      for (int ci = 0; ci < 2; ci++) {
        int col = cb + ci*16 + n16;
        pS[ri][ci] = PS[(size_t)(node0+ri)*128 + col];
        pT[ri][ci] = PT[(size_t)(node0+ri)*128 + col];
      }
    f32x4 aS[4][2], aT[4][2];
#pragma unroll
    for (int ri = 0; ri < 4; ri++)
#pragma unroll
      for (int ci = 0; ci < 2; ci++) {
        aS[ri][ci] = (f32x4){0.f,0.f,0.f,0.f};
        aT[ri][ci] = (f32x4){0.f,0.f,0.f,0.f};
      }
#pragma unroll
    for (int ks = 0; ks < 2; ks++) {
      short8 af[4];
#pragma unroll
      for (int ri = 0; ri < 4; ri++) {
        int m = ri*16 + n16;
        af[ri] = *(const short8*)&dlds[m*64 + ((ks*4+q) ^ (m & 7))*8];
      }
#pragma unroll
      for (int ci = 0; ci < 2; ci++) {
        int col = cb + ci*16 + n16;
        short8 bS = *(const short8*)(sW1t + col*128 + 64 + (ks*4+q)*8);
        short8 bT = *(const short8*)(tW1t + col*128 + 64 + (ks*4+q)*8);
#pragma unroll
        for (int ri = 0; ri < 4; ri++) {
          aS[ri][ci] = __builtin_amdgcn_mfma_f32_16x16x32_bf16(af[ri], bS, aS[ri][ci], 0, 0, 0);
          aT[ri][ci] = __builtin_amdgcn_mfma_f32_16x16x32_bf16(af[ri], bT, aT[ri][ci], 0, 0, 0);
        }
      }
    }
#pragma unroll
    for (int ci = 0; ci < 2; ci++)
#pragma unroll
      for (int ri = 0; ri < 4; ri++)
#pragma unroll
        for (int r = 0; r < 4; r++) {
          float vS = aS[ri][ci][r] + pS[ri][ci];
          float vT = aT[ri][ci][r] + pT[ri][ci];
          psS[ci] += vS; ps2S[ci] += vS*vS;
          psT[ci] += vT; ps2T[ci] += vT*vT;
        }
  }
#pragma unroll
  for (int ci = 0; ci < 2; ci++) {
    int col = cb + ci*16 + n16;
    float a = psS[ci], a2 = ps2S[ci], b2v = psT[ci], b3 = ps2T[ci];
    a   += __shfl_xor(a, 16, 64);   a   += __shfl_xor(a, 32, 64);
    a2  += __shfl_xor(a2, 16, 64);  a2  += __shfl_xor(a2, 32, 64);
    b2v += __shfl_xor(b2v, 16, 64); b2v += __shfl_xor(b2v, 32, 64);
    b3  += __shfl_xor(b3, 16, 64);  b3  += __shfl_xor(b3, 32, 64);
    if (q == 0) {
      atomicAdd(&statS[col], a);
      atomicAdd(&statS[128 + col], a2);
      atomicAdd(&statT[col], b2v);
      atomicAdd(&statT[128 + col], b3);
    }
  }
}

// ---------------- BN passes over D + P (round-7 config: 256,2) ----------------
// MODE 1: h1 -> bn1+relu -> GEMM2 -> stats2
// MODE 2: -> bn2+relu -> max over K -> [xs|xt] in LDS -> @f_W -> gout + statF
template<int MODE>
__global__ __launch_bounds__(256, 2) void mlp_pass2(
    const unsigned short* __restrict__ D,
    const float* __restrict__ PS, const float* __restrict__ PT,
    const unsigned short* __restrict__ sW1t, const unsigned short* __restrict__ sW2t,
    const unsigned short* __restrict__ tW1t, const unsigned short* __restrict__ tW2t,
    const unsigned short* __restrict__ fWt,
    const float* __restrict__ affS1, const float* __restrict__ affS2,
    const float* __restrict__ affT1, const float* __restrict__ affT2,
    float* __restrict__ statS, float* __restrict__ statT,
    float* __restrict__ statF, float* __restrict__ gout) {
  __shared__ unsigned short dlds[64*64];
  __shared__ unsigned short atile[64*128];
  __shared__ unsigned short xtile[(MODE == 2) ? 16*256 : 64];
  int wave = threadIdx.x >> 6;
  int lane = threadIdx.x & 63;
  int n16 = lane & 15, q = lane >> 4;
  int cb = wave * 32;

  float s1S[2], h1S[2], s2S[2], h2S[2];
  float s1T[2], h1T[2], s2T[2], h2T[2];
#pragma unroll
  for (int ci = 0; ci < 2; ci++) {
    int col = cb + ci*16 + n16;
    s1S[ci] = affS1[col]; h1S[ci] = affS1[128 + col];
    s1T[ci] = affT1[col]; h1T[ci] = affT1[128 + col];
  }
  if (MODE == 2) {
#pragma unroll
    for (int ci = 0; ci < 2; ci++) {
      int col = cb + ci*16 + n16;
      s2S[ci] = affS2[col]; h2S[ci] = affS2[128 + col];
      s2T[ci] = affT2[col]; h2T[ci] = affT2[128 + col];
    }
  }
  float psS[2] = {0,0}, ps2S[2] = {0,0};
  float psT[2] = {0,0}, ps2T[2] = {0,0};

  for (int it = 0; it < 4; it++) {
    int tile = blockIdx.x*4 + it;
    __syncthreads();
    {
      const ushort8* src = (const ushort8*)(D + (size_t)tile*4096);
      ushort8* dst = (ushort8*)dlds;
      dst[threadIdx.x] = src[threadIdx.x];
      dst[threadIdx.x + 256] = src[threadIdx.x + 256];
    }
    __syncthreads();
    int node0 = tile*4;
    float pS[4][2], pT[4][2];
#pragma unroll
    for (int ri = 0; ri < 4; ri++)
#pragma unroll
      for (int ci = 0; ci < 2; ci++) {
        int col = cb + ci*16 + n16;
        pS[ri][ci] = PS[(size_t)(node0+ri)*128 + col];
        pT[ri][ci] = PT[(size_t)(node0+ri)*128 + col];
      }

#pragma unroll
    for (int st = 0; st < 2; st++) {
      const unsigned short* W1t = st ? tW1t : sW1t;
      const unsigned short* W2t = st ? tW2t : sW2t;
      const float* sc1 = st ? s1T : s1S;  const float* sh1 = st ? h1T : h1S;
      const float* sc2 = st ? s2T : s2S;  const float* sh2 = st ? h2T : h2S;
      float (*pp)[2] = st ? pT : pS;
      float* ps  = st ? psT : psS;
      float* ps2 = st ? ps2T : ps2S;

      // GEMM1 (bottom half, K=64): h1 = P + D @ W1bot
      f32x4 acc[4][2];
#pragma unroll
      for (int ri = 0; ri < 4; ri++)
#pragma unroll
        for (int ci = 0; ci < 2; ci++)
          acc[ri][ci] = (f32x4){0.f,0.f,0.f,0.f};
#pragma unroll
      for (int ks = 0; ks < 2; ks++) {
        short8 af[4], bf[2];
#pragma unroll
        for (int ri = 0; ri < 4; ri++) {
          int mm = ri*16 + n16;
          af[ri] = *(const short8*)&dlds[mm*64 + ((ks*4+q) ^ (mm & 7))*8];
        }
#pragma unroll
        for (int ci = 0; ci < 2; ci++) {
          int col = cb + ci*16 + n16;
          bf[ci] = *(const short8*)(W1t + col*128 + 64 + (ks*4+q)*8);
        }
#pragma unroll
        for (int ri = 0; ri < 4; ri++)
#pragma unroll
          for (int ci = 0; ci < 2; ci++)
            acc[ri][ci] = __builtin_amdgcn_mfma_f32_16x16x32_bf16(af[ri], bf[ci], acc[ri][ci], 0, 0, 0);
      }
      // bn1 + relu -> a-tile (bf16, swizzled)
#pragma unroll
      for (int ri = 0; ri < 4; ri++)
#pragma unroll
        for (int ci = 0; ci < 2; ci++) {
          int colL = cb + ci*16 + n16;
          int kc8 = colL >> 3;
#pragma unroll
          for (int r = 0; r < 4; r++) {
            float v = acc[ri][ci][r] + pp[ri][ci];
            v = fmaxf(v * sc1[ci] + sh1[ci], 0.f);
            int rowL = ri*16 + q*4 + r;
            int pos = ((kc8 ^ (rowL & 7)) << 3) + (colL & 7);
            atile[rowL*128 + pos] = f2bf(v);
          }
        }
      __syncthreads();
      // GEMM2 (K=128)
      f32x4 acc2[4][2];
#pragma unroll
      for (int ri = 0; ri < 4; ri++)
#pragma unroll
        for (int ci = 0; ci < 2; ci++)
          acc2[ri][ci] = (f32x4){0.f,0.f,0.f,0.f};
#pragma unroll
      for (int ks = 0; ks < 4; ks++) {
        short8 a2[4], bf[2];
#pragma unroll
        for (int ri = 0; ri < 4; ri++) {
          int mm = ri*16 + n16;
          int kc8 = (ks*4 + q) ^ (mm & 7);
          a2[ri] = *(const short8*)&atile[mm*128 + kc8*8];
        }
#pragma unroll
        for (int ci = 0; ci < 2; ci++) {
          int col = cb + ci*16 + n16;
          bf[ci] = *(const short8*)(W2t + col*128 + ks*32 + q*8);
        }
#pragma unroll
        for (int ri = 0; ri < 4; ri++)
#pragma unroll
          for (int ci = 0; ci < 2; ci++)
            acc2[ri][ci] = __builtin_amdgcn_mfma_f32_16x16x32_bf16(a2[ri], bf[ci], acc2[ri][ci], 0, 0, 0);
      }
      if (MODE == 1) {
#pragma unroll
        for (int ci = 0; ci < 2; ci++)
#pragma unroll
          for (int ri = 0; ri < 4; ri++)
#pragma unroll
            for (int r = 0; r < 4; r++) {
              float v = acc2[ri][ci][r];
              ps[ci] += v; ps2[ci] += v*v;
            }
      } else {
        // bn2+relu+max over K -> xtile (16 nodes x 256 ch, swizzled for final GEMM)
#pragma unroll
        for (int ri = 0; ri < 4; ri++)
#pragma unroll
          for (int ci = 0; ci < 2; ci++) {
            int col = cb + ci*16 + n16;
            float vm = 0.f;
#pragma unroll
            for (int r = 0; r < 4; r++) {
              float v = fmaxf(acc2[ri][ci][r] * sc2[ci] + sh2[ci], 0.f);
              vm = fmaxf(vm, v);
            }
            vm = fmaxf(vm, __shfl_xor(vm, 16, 64));
            vm = fmaxf(vm, __shfl_xor(vm, 32, 64));
            if (q == 0) {
              int ln = it*4 + ri;               // local node 0..15
              int fcol = st*128 + col;          // 0..255
              int kc8 = fcol >> 3;
              int pos = ((kc8 ^ (ln & 7)) << 3) + (fcol & 7);
              xtile[ln*256 + pos] = f2bf(vm);
            }
          }
      }
      if (st == 0) __syncthreads();
    }
  }
  if (MODE == 1) {
#pragma unroll
    for (int ci = 0; ci < 2; ci++) {
      int col = cb + ci*16 + n16;
      float a = psS[ci], a2 = ps2S[ci], b = psT[ci], b2 = ps2T[ci];
      a  += __shfl_xor(a, 16, 64);  a  += __shfl_xor(a, 32, 64);
      a2 += __shfl_xor(a2, 16, 64); a2 += __shfl_xor(a2, 32, 64);
      b  += __shfl_xor(b, 16, 64);  b  += __shfl_xor(b, 32, 64);
      b2 += __shfl_xor(b2, 16, 64); b2 += __shfl_xor(b2, 32, 64);
      if (q == 0) {
        atomicAdd(&statS[col], a);
        atomicAdd(&statS[128 + col], a2);
        atomicAdd(&statT[col], b);
        atomicAdd(&statT[128 + col], b2);
      }
    }
  } else {
    // fused final linear: gout = [xs|xt] @ f_W (16 nodes), + statF
    __syncthreads();
    f32x4 facc[2];
#pragma unroll
    for (int ci = 0; ci < 2; ci++) facc[ci] = (f32x4){0.f,0.f,0.f,0.f};
#pragma unroll
    for (int ks = 0; ks < 8; ks++) {
      int kc8 = (ks*4 + q) ^ (n16 & 7);
      short8 af = *(const short8*)&xtile[n16*256 + kc8*8];
#pragma unroll
      for (int ci = 0; ci < 2; ci++) {
        int col = cb + ci*16 + n16;
        short8 bf = *(const short8*)(fWt + col*256 + ks*32 + q*8);
        facc[ci] = __builtin_amdgcn_mfma_f32_16x16x32_bf16(af, bf, facc[ci], 0, 0, 0);
      }
    }
    int nodeBase = blockIdx.x * 16;
    float fs[2] = {0,0}, fs2[2] = {0,0};
#pragma unroll
    for (int ci = 0; ci < 2; ci++) {
      int col = cb + ci*16 + n16;
#pragma unroll
      for (int r = 0; r < 4; r++) {
        float v = facc[ci][r];
        gout[(size_t)(nodeBase + q*4 + r)*128 + col] = v;
        fs[ci] += v; fs2[ci] += v*v;
      }
      float a = fs[ci], a2 = fs2[ci];
      a  += __shfl_xor(a, 16, 64);  a  += __shfl_xor(a, 32, 64);
      a2 += __shfl_xor(a2, 16, 64); a2 += __shfl_xor(a2, 32, 64);
      if (q == 0) {
        atomicAdd(&statF[col], a);
        atomicAdd(&statF[128 + col], a2);
      }
    }
  }
}

// ---------------- finalize BN stats -> (scale, shift) ----------------
__global__ void finalize_kernel(const float* __restrict__ stats,
                                const float* __restrict__ g,
                                const float* __restrict__ be,
                                float* __restrict__ aff, float invcount) {
  int c = threadIdx.x;
  if (c < 128) {
    float mean = stats[c] * invcount;
    float var = stats[128 + c] * invcount - mean*mean;
    float scale = g[c] / sqrtf(var + EPSV);
    aff[c] = scale;
    aff[128 + c] = be[c] - mean * scale;
  }
}

__global__ void apply_bn_kernel(float* __restrict__ out, const float* __restrict__ aff) {
  int i = blockIdx.x * blockDim.x + threadIdx.x;
  if (i < NS*NH) {
    int c = i & 127;
    out[i] = fmaxf(out[i] * aff[c] + aff[128 + c], 0.f);
  }
}

extern "C" void kernel_launch(void* const* d_in, const int* in_sizes, int n_in,
                              void* d_out, int out_size, void* d_ws, size_t ws_size,
                              hipStream_t stream) {
  const float* x   = (const float*)d_in[0];
  const float* sW1 = (const float*)d_in[2];
  const float* sg1 = (const float*)d_in[4];
  const float* sbe1= (const float*)d_in[5];
  const float* sW2 = (const float*)d_in[6];
  const float* sg2 = (const float*)d_in[8];
  const float* sbe2= (const float*)d_in[9];
  const float* tW1 = (const float*)d_in[10];
  const float* tg1 = (const float*)d_in[12];
  const float* tbe1= (const float*)d_in[13];
  const float* tW2 = (const float*)d_in[14];
  const float* tg2 = (const float*)d_in[16];
  const float* tbe2= (const float*)d_in[17];
  const float* fW  = (const float*)d_in[18];
  const float* fg  = (const float*)d_in[20];
  const float* fbe = (const float*)d_in[21];
  float* out = (float*)d_out;

  char* w = (char*)d_ws;
  float* sq = (float*)w;                 w += (size_t)NS*4;
  int* nbr = (int*)w;                    w += (size_t)NSK*4;
  unsigned short* sW1t = (unsigned short*)w; w += 32768;
  unsigned short* sW2t = (unsigned short*)w; w += 32768;
  unsigned short* tW1t = (unsigned short*)w; w += 32768;
  unsigned short* tW2t = (unsigned short*)w; w += 32768;
  unsigned short* fWt  = (unsigned short*)w; w += 65536;
  float* stats = (float*)w;              w += 2560*4;
  unsigned short* xh = (unsigned short*)w; w += (size_t)NS*64*2;
  unsigned short* xl = (unsigned short*)w; w += (size_t)NS*64*2;
  unsigned short* Dg = (unsigned short*)w; w += (size_t)NSK*64*2;
  float* PS = (float*)w;                 w += (size_t)NS*128*4;
  float* PT = (float*)w;                 w += (size_t)NS*128*4;

  float* st_s1 = stats;        float* af_s1 = stats + 256;
  float* st_s2 = stats + 512;  float* af_s2 = stats + 768;
  float* st_t1 = stats + 1024; float* af_t1 = stats + 1280;
  float* st_t2 = stats + 1536; float* af_t2 = stats + 1792;
  float* st_f  = stats + 2048; float* af_f  = stats + 2304;

  hipMemsetAsync(stats, 0, 2560*4, stream);
  prep_weights<<<(4*16384 + 128*256 + 255)/256, 256, 0, stream>>>(
      sW1, sW2, tW1, tW2, fW, sW1t, sW2t, tW1t, tW2t, fWt);
  prep_x<<<NS/256, 256, 0, stream>>>(x, sq, xh, xl);
  knn5_kernel<<<NB*32, 256, 0, stream>>>(xh, xl, sq, nbr);
  pnode_kernel<<<NS/64, 256, 0, stream>>>(x, sW1t, tW1t, PS, PT);
  dstat_kernel<<<2048, 256, 0, stream>>>(x, nbr, sW1t, tW1t, PS, PT, Dg, st_s1, st_t1);

  const float inv1 = 1.f/(float)NSK, invf = 1.f/(float)NS;
  finalize_kernel<<<1,128,0,stream>>>(st_s1, sg1, sbe1, af_s1, inv1);
  finalize_kernel<<<1,128,0,stream>>>(st_t1, tg1, tbe1, af_t1, inv1);
  mlp_pass2<1><<<2048,256,0,stream>>>(Dg, PS, PT, sW1t, sW2t, tW1t, tW2t, fWt,
      af_s1, nullptr, af_t1, nullptr, st_s2, st_t2, nullptr, nullptr);
  finalize_kernel<<<1,128,0,stream>>>(st_s2, sg2, sbe2, af_s2, inv1);
  finalize_kernel<<<1,128,0,stream>>>(st_t2, tg2, tbe2, af_t2, inv1);
  mlp_pass2<2><<<2048,256,0,stream>>>(Dg, PS, PT, sW1t, sW2t, tW1t, tW2t, fWt,
      af_s1, af_s2, af_t1, af_t2, nullptr, nullptr, st_f, out);
  finalize_kernel<<<1,128,0,stream>>>(st_f, fg, fbe, af_f, invf);
  apply_bn_kernel<<<(NS*NH)/256, 256, 0, stream>>>(out, af_f);
}

// Round 11
// 505.922 us; speedup vs baseline: 1.7192x; 1.1158x over previous
//
#include <hip/hip_runtime.h>
#include <hip/hip_bf16.h>
#include <stdint.h>

#define NB 16
#define NN 2048
#define NC 64
#define NH 128
#define NK 16
#define NS (NB*NN)
#define NSK (NS*NK)
#define EPSV 1e-5f

typedef __attribute__((ext_vector_type(8))) short short8;
typedef __attribute__((ext_vector_type(8))) _Float16 half8;
typedef __attribute__((ext_vector_type(8))) unsigned short ushort8;
typedef __attribute__((ext_vector_type(4))) float f32x4;

__device__ __forceinline__ unsigned short f2bf(float x) {
  union { float f; unsigned u; } v; v.f = x;
  unsigned r = v.u + 0x7fffu + ((v.u >> 16) & 1u);
  return (unsigned short)(r >> 16);
}

__device__ __forceinline__ unsigned orderf(float f) {
  unsigned u = __float_as_uint(f);
  return u ^ ((unsigned)((int)u >> 31) | 0x80000000u);
}

__device__ __forceinline__ float unorderf(unsigned whi) {
  return (whi == 0xffffffffu) ? __builtin_inff()
       : __uint_as_float((whi & 0x80000000u) ? (whi ^ 0x80000000u) : ~whi);
}

__device__ __forceinline__ unsigned long long shfl_xor_u64(unsigned long long v, int m) {
  unsigned lo = (unsigned)(v & 0xffffffffull);
  unsigned hi = (unsigned)(v >> 32);
  lo = __shfl_xor(lo, m, 64);
  hi = __shfl_xor(hi, m, 64);
  return (((unsigned long long)hi) << 32) | lo;
}

// ---------------- prep: squared norms + split-fp16 (hi, lo) ----------------
__global__ void prep_x(const float* __restrict__ x, float* __restrict__ sq,
                       unsigned short* __restrict__ xh, unsigned short* __restrict__ xl) {
  int i = blockIdx.x * blockDim.x + threadIdx.x;
  if (i >= NS) return;
  const float4* x4 = (const float4*)(x + (size_t)i * NC);
  float s = 0.f;
#pragma unroll
  for (int k = 0; k < 8; k++) {
    float4 a = x4[2*k], b = x4[2*k+1];
    float f[8] = {a.x,a.y,a.z,a.w,b.x,b.y,b.z,b.w};
    ushort8 hv, lv;
#pragma unroll
    for (int j = 0; j < 8; j++) {
      float v = f[j];
      s += v*v;
      _Float16 h = (_Float16)v;
      float r = v - (float)h;
      _Float16 l = (_Float16)r;
      union { _Float16 ff; unsigned short u; } ch, cl;
      ch.ff = h; cl.ff = l;
      hv[j] = ch.u; lv[j] = cl.u;
    }
    *(ushort8*)(xh + (size_t)i*64 + k*8) = hv;
    *(ushort8*)(xl + (size_t)i*64 + k*8) = lv;
  }
  sq[i] = s;
}

// ---------------- kNN v5b: register MFMA + shared row threshold + cond. stash ----------------
__global__ __launch_bounds__(256) void knn5_kernel(const unsigned short* __restrict__ xh,
                                                   const unsigned short* __restrict__ xl,
                                                   const float* __restrict__ sq,
                                                   int* __restrict__ nbr) {
  __shared__ unsigned short rAh[64*64], rAl[64*64];
  __shared__ unsigned short cBh[64*64], cBl[64*64];
  __shared__ float sqc[64];
  __shared__ float d2s[256*17];
  int b = blockIdx.x >> 5;
  int rb = blockIdx.x & 31;
  int w = threadIdx.x >> 6, lane = threadIdx.x & 63;
  int n16 = lane & 15, q = lane >> 4;
  int rowbase = b*NN + rb*64;
  float* myd2 = &d2s[threadIdx.x * 17];

  {
    int r = threadIdx.x >> 2;
    int c0 = (threadIdx.x & 3) * 2;
#pragma unroll
    for (int cc = 0; cc < 2; cc++) {
      int c = c0 + cc;
      int pos = (c ^ (r & 7)) * 8;
      *(ushort8*)&rAh[r*64 + pos] = *(const ushort8*)(xh + (size_t)(rowbase + r)*64 + c*8);
      *(ushort8*)&rAl[r*64 + pos] = *(const ushort8*)(xl + (size_t)(rowbase + r)*64 + c*8);
    }
  }
  __syncthreads();
  half8 bh[2], bl[2];
  int m = w*16 + n16;
#pragma unroll
  for (int ks = 0; ks < 2; ks++) {
    int pos = ((ks*4 + q) ^ (m & 7)) * 8;
    bh[ks] = *(const half8*)&rAh[m*64 + pos];
    bl[ks] = *(const half8*)&rAl[m*64 + pos];
  }
  float sqr = sq[rowbase + m];

  unsigned long long keys[16];
#pragma unroll
  for (int i = 0; i < 16; i++) keys[i] = ~0ull;
  float wd2 = __builtin_inff();

  for (int ch = 0; ch < 32; ch++) {
    int colbase = b*NN + ch*64;
    __syncthreads();
    {
      int r = threadIdx.x >> 2;
      int c0 = (threadIdx.x & 3) * 2;
#pragma unroll
      for (int cc = 0; cc < 2; cc++) {
        int c = c0 + cc;
        int pos = (c ^ (r & 7)) * 8;
        *(ushort8*)&cBh[r*64 + pos] = *(const ushort8*)(xh + (size_t)(colbase + r)*64 + c*8);
        *(ushort8*)&cBl[r*64 + pos] = *(const ushort8*)(xl + (size_t)(colbase + r)*64 + c*8);
      }
      if (threadIdx.x < 64) sqc[threadIdx.x] = sq[colbase + threadIdx.x];
    }
    __syncthreads();
    f32x4 acc[4];
#pragma unroll
    for (int ci = 0; ci < 4; ci++) acc[ci] = (f32x4){0.f,0.f,0.f,0.f};
#pragma unroll
    for (int ks = 0; ks < 2; ks++) {
#pragma unroll
      for (int ci = 0; ci < 4; ci++) {
        int n = ci*16 + n16;
        int pos = ((ks*4 + q) ^ (n & 7)) * 8;
        half8 ah_ = *(const half8*)&cBh[n*64 + pos];
        half8 al_ = *(const half8*)&cBl[n*64 + pos];
        acc[ci] = __builtin_amdgcn_mfma_f32_16x16x32_f16(ah_, bh[ks], acc[ci], 0, 0, 0);
        acc[ci] = __builtin_amdgcn_mfma_f32_16x16x32_f16(al_, bh[ks], acc[ci], 0, 0, 0);
        acc[ci] = __builtin_amdgcn_mfma_f32_16x16x32_f16(ah_, bl[ks], acc[ci], 0, 0, 0);
      }
    }
    float d2v[16];
    unsigned mask = 0;
#pragma unroll
    for (int ci = 0; ci < 4; ci++)
#pragma unroll
      for (int r = 0; r < 4; r++) {
        int idx = ci*4 + r;
        float d2 = fmaf(-2.f, acc[ci][r], sqr + sqc[ci*16 + q*4 + r]);
        d2v[idx] = d2;
        mask |= (d2 <= wd2) ? (1u << idx) : 0u;
      }
    if (mask) {
#pragma unroll
      for (int i = 0; i < 16; i++) myd2[i] = d2v[i];
      while (mask) {
        int i = __builtin_ctz(mask);
        mask &= mask - 1;
        float dd = myd2[i];
        if (dd > wd2) continue;
        int col = colbase + (i >> 2)*16 + q*4 + (i & 3);
        unsigned long long key = ((unsigned long long)orderf(dd) << 32) | (unsigned)col;
#pragma unroll
        for (int j = 0; j < 16; j++) {
          bool cl = key < keys[j];
          unsigned long long lo = cl ? key : keys[j];
          key = cl ? keys[j] : key;
          keys[j] = lo;
        }
        wd2 = fminf(wd2, unorderf((unsigned)(keys[15] >> 32)));
      }
    }
    {
      unsigned whi = (unsigned)(keys[15] >> 32);
      unsigned o = __shfl_xor(whi, 16, 64); whi = (o < whi) ? o : whi;
      o = __shfl_xor(whi, 32, 64); whi = (o < whi) ? o : whi;
      wd2 = unorderf(whi);
    }
  }
  for (int j = 0; j < NK; j++) {
    unsigned long long mk = keys[0];
#pragma unroll
    for (int i = 1; i < 16; i++) mk = (keys[i] < mk) ? keys[i] : mk;
    unsigned long long o = shfl_xor_u64(mk, 16); mk = (o < mk) ? o : mk;
    o = shfl_xor_u64(mk, 32); mk = (o < mk) ? o : mk;
#pragma unroll
    for (int i = 0; i < 16; i++) if (keys[i] == mk) keys[i] = ~0ull;
    if (q == 0) nbr[(size_t)(rowbase + m)*NK + j] = (int)(mk & 0xffffffffu);
  }
}

// ---------------- weight prep ----------------
__global__ void prep_weights(const float* __restrict__ sW1, const float* __restrict__ sW2,
                             const float* __restrict__ tW1, const float* __restrict__ tW2,
                             const float* __restrict__ fW,
                             unsigned short* __restrict__ sW1t, unsigned short* __restrict__ sW2t,
                             unsigned short* __restrict__ tW1t, unsigned short* __restrict__ tW2t,
                             unsigned short* __restrict__ fWt) {
  int i = blockIdx.x * blockDim.x + threadIdx.x;
  if (i < 4*16384) {
    int mi = i >> 14, e = i & 16383;
    int h = e >> 7, k = e & 127;
    const float* src = (mi==0) ? sW1 : (mi==1) ? sW2 : (mi==2) ? tW1 : tW2;
    unsigned short* dst = (mi==0) ? sW1t : (mi==1) ? sW2t : (mi==2) ? tW1t : tW2t;
    dst[h*128 + k] = f2bf(src[k*128 + h]);
  } else {
    int e = i - 4*16384;
    if (e < 128*256) {
      int h = e >> 8, k = e & 255;
      fWt[h*256 + k] = f2bf(fW[k*128 + h]);
    }
  }
}

// ---------------- per-node term: P = bf16(x) @ W1_top (both streams) ----------------
__global__ __launch_bounds__(256) void pnode_kernel(
    const float* __restrict__ x,
    const unsigned short* __restrict__ sW1t, const unsigned short* __restrict__ tW1t,
    float* __restrict__ PS, float* __restrict__ PT) {
  __shared__ unsigned short xt_[64*64];
  int rowbase = blockIdx.x * 64;
  int lane = threadIdx.x & 63;
  int wave = threadIdx.x >> 6;
  int n16 = lane & 15, q = lane >> 4;
  int cb = wave * 32;
  {
    int r = threadIdx.x >> 2, part = threadIdx.x & 3;
    const float4* xp = (const float4*)(x + (size_t)(rowbase + r) * NC) + part*4;
#pragma unroll
    for (int cc = 0; cc < 2; cc++) {
      int c = part*2 + cc;
      float4 a = xp[cc*2], b = xp[cc*2+1];
      int pos = (c ^ (r & 7)) * 8;
      unsigned short* d = &xt_[r*64 + pos];
      d[0]=f2bf(a.x); d[1]=f2bf(a.y); d[2]=f2bf(a.z); d[3]=f2bf(a.w);
      d[4]=f2bf(b.x); d[5]=f2bf(b.y); d[6]=f2bf(b.z); d[7]=f2bf(b.w);
    }
  }
  __syncthreads();
  f32x4 aS[4][2], aT[4][2];
#pragma unroll
  for (int ri = 0; ri < 4; ri++)
#pragma unroll
    for (int ci = 0; ci < 2; ci++) {
      aS[ri][ci] = (f32x4){0.f,0.f,0.f,0.f};
      aT[ri][ci] = (f32x4){0.f,0.f,0.f,0.f};
    }
#pragma unroll
  for (int ks = 0; ks < 2; ks++) {
    short8 af[4];
#pragma unroll
    for (int ri = 0; ri < 4; ri++) {
      int m = ri*16 + n16;
      af[ri] = *(const short8*)&xt_[m*64 + (((ks*4+q) ^ (m & 7)))*8];
    }
#pragma unroll
    for (int ci = 0; ci < 2; ci++) {
      int col = cb + ci*16 + n16;
      short8 bS = *(const short8*)(sW1t + col*128 + (ks*4+q)*8);
      short8 bT = *(const short8*)(tW1t + col*128 + (ks*4+q)*8);
#pragma unroll
      for (int ri = 0; ri < 4; ri++) {
        aS[ri][ci] = __builtin_amdgcn_mfma_f32_16x16x32_bf16(af[ri], bS, aS[ri][ci], 0, 0, 0);
        aT[ri][ci] = __builtin_amdgcn_mfma_f32_16x16x32_bf16(af[ri], bT, aT[ri][ci], 0, 0, 0);
      }
    }
  }
#pragma unroll
  for (int ri = 0; ri < 4; ri++)
#pragma unroll
    for (int ci = 0; ci < 2; ci++) {
      int col = cb + ci*16 + n16;
#pragma unroll
      for (int r = 0; r < 4; r++) {
        int row = rowbase + ri*16 + q*4 + r;
        PS[(size_t)row*128 + col] = aS[ri][ci][r];
        PT[(size_t)row*128 + col] = aT[ri][ci][r];
      }
    }
}

// ---------------- fused D-build + MODE0 stats (256,2, dual-stream) ----------------
__global__ __launch_bounds__(256, 2) void dstat_kernel(
    const float* __restrict__ x, const int* __restrict__ nbr,
    const unsigned short* __restrict__ sW1t, const unsigned short* __restrict__ tW1t,
    const float* __restrict__ PS, const float* __restrict__ PT,
    unsigned short* __restrict__ D,
    float* __restrict__ statS, float* __restrict__ statT) {
  __shared__ unsigned short dlds[64*64];
  int wave = threadIdx.x >> 6, lane = threadIdx.x & 63;
  int n16 = lane & 15, q = lane >> 4;
  int cb = wave * 32;
  int g = blockIdx.x & 15, sub = blockIdx.x >> 4;
  float psS[2]={0,0}, ps2S[2]={0,0}, psT[2]={0,0}, ps2T[2]={0,0};

  for (int it = 0; it < 4; it++) {
    int tile = g*512 + sub*4 + it;
    __syncthreads();
    {
      int r4 = threadIdx.x >> 2, part = threadIdx.x & 3;
      int s = tile*64 + r4;
      int node = s >> 4;
      int ng = nbr[s];
      const float4* xi = (const float4*)(x + (size_t)node * NC) + part*4;
      const float4* xj = (const float4*)(x + (size_t)ng  * NC) + part*4;
      unsigned short* dstg = D + (size_t)tile*4096 + (size_t)r4*64;
#pragma unroll
      for (int cc = 0; cc < 2; cc++) {
        int c = part*2 + cc;
        float4 a0 = xi[cc*2], a1 = xi[cc*2+1];
        float4 b0 = xj[cc*2], b1 = xj[cc*2+1];
        int pos = (c ^ (r4 & 7)) * 8;
        ushort8 dv;
        dv[0]=f2bf(b0.x-a0.x); dv[1]=f2bf(b0.y-a0.y); dv[2]=f2bf(b0.z-a0.z); dv[3]=f2bf(b0.w-a0.w);
        dv[4]=f2bf(b1.x-a1.x); dv[5]=f2bf(b1.y-a1.y); dv[6]=f2bf(b1.z-a1.z); dv[7]=f2bf(b1.w-a1.w);
        *(ushort8*)(dstg + pos) = dv;
        *(ushort8*)(dlds + r4*64 + pos) = dv;
      }
    }
    __syncthreads();
    int node0 = tile*4;
    float pS[4][2], pT[4][2];
#pragma unroll
    for (int ri = 0; ri < 4; ri++)
#pragma unroll
      for (int ci = 0; ci < 2; ci++) {
        int col = cb + ci*16 + n16;
        pS[ri][ci] = PS[(size_t)(node0+ri)*128 + col];
        pT[ri][ci] = PT[(size_t)(node0+ri)*128 + col];
      }
    f32x4 aS[4][2], aT[4][2];
#pragma unroll
    for (int ri = 0; ri < 4; ri++)
#pragma unroll
      for (int ci = 0; ci < 2; ci++) {
        aS[ri][ci] = (f32x4){0.f,0.f,0.f,0.f};
        aT[ri][ci] = (f32x4){0.f,0.f,0.f,0.f};
      }
#pragma unroll
    for (int ks = 0; ks < 2; ks++) {
      short8 af[4];
#pragma unroll
      for (int ri = 0; ri < 4; ri++) {
        int m = ri*16 + n16;
        af[ri] = *(const short8*)&dlds[m*64 + ((ks*4+q) ^ (m & 7))*8];
      }
#pragma unroll
      for (int ci = 0; ci < 2; ci++) {
        int col = cb + ci*16 + n16;
        short8 bS = *(const short8*)(sW1t + col*128 + 64 + (ks*4+q)*8);
        short8 bT = *(const short8*)(tW1t + col*128 + 64 + (ks*4+q)*8);
#pragma unroll
        for (int ri = 0; ri < 4; ri++) {
          aS[ri][ci] = __builtin_amdgcn_mfma_f32_16x16x32_bf16(af[ri], bS, aS[ri][ci], 0, 0, 0);
          aT[ri][ci] = __builtin_amdgcn_mfma_f32_16x16x32_bf16(af[ri], bT, aT[ri][ci], 0, 0, 0);
        }
      }
    }
#pragma unroll
    for (int ci = 0; ci < 2; ci++)
#pragma unroll
      for (int ri = 0; ri < 4; ri++)
#pragma unroll
        for (int r = 0; r < 4; r++) {
          float vS = aS[ri][ci][r] + pS[ri][ci];
          float vT = aT[ri][ci][r] + pT[ri][ci];
          psS[ci] += vS; ps2S[ci] += vS*vS;
          psT[ci] += vT; ps2T[ci] += vT*vT;
        }
  }
#pragma unroll
  for (int ci = 0; ci < 2; ci++) {
    int col = cb + ci*16 + n16;
    float a = psS[ci], a2 = ps2S[ci], b2v = psT[ci], b3 = ps2T[ci];
    a   += __shfl_xor(a, 16, 64);   a   += __shfl_xor(a, 32, 64);
    a2  += __shfl_xor(a2, 16, 64);  a2  += __shfl_xor(a2, 32, 64);
    b2v += __shfl_xor(b2v, 16, 64); b2v += __shfl_xor(b2v, 32, 64);
    b3  += __shfl_xor(b3, 16, 64);  b3  += __shfl_xor(b3, 32, 64);
    if (q == 0) {
      atomicAdd(&statS[col], a);
      atomicAdd(&statS[128 + col], a2);
      atomicAdd(&statT[col], b2v);
      atomicAdd(&statT[128 + col], b3);
    }
  }
}

// ---------------- mid pass: h1 -> bn1+relu -> GEMM2 -> stats2 + per-node max/min of h2 ----------------
__global__ __launch_bounds__(256, 2) void mlp_mid(
    const unsigned short* __restrict__ D,
    const float* __restrict__ PS, const float* __restrict__ PT,
    const unsigned short* __restrict__ sW1t, const unsigned short* __restrict__ sW2t,
    const unsigned short* __restrict__ tW1t, const unsigned short* __restrict__ tW2t,
    const float* __restrict__ affS1, const float* __restrict__ affT1,
    float* __restrict__ statS, float* __restrict__ statT,
    float* __restrict__ HmxS, float* __restrict__ HmnS,
    float* __restrict__ HmxT, float* __restrict__ HmnT) {
  __shared__ unsigned short dlds[64*64];
  __shared__ unsigned short atile[64*128];
  int wave = threadIdx.x >> 6;
  int lane = threadIdx.x & 63;
  int n16 = lane & 15, q = lane >> 4;
  int cb = wave * 32;

  float s1S[2], h1S[2], s1T[2], h1T[2];
#pragma unroll
  for (int ci = 0; ci < 2; ci++) {
    int col = cb + ci*16 + n16;
    s1S[ci] = affS1[col]; h1S[ci] = affS1[128 + col];
    s1T[ci] = affT1[col]; h1T[ci] = affT1[128 + col];
  }
  float psS[2] = {0,0}, ps2S[2] = {0,0};
  float psT[2] = {0,0}, ps2T[2] = {0,0};

  for (int it = 0; it < 4; it++) {
    int tile = blockIdx.x*4 + it;
    __syncthreads();
    {
      const ushort8* src = (const ushort8*)(D + (size_t)tile*4096);
      ushort8* dst = (ushort8*)dlds;
      dst[threadIdx.x] = src[threadIdx.x];
      dst[threadIdx.x + 256] = src[threadIdx.x + 256];
    }
    __syncthreads();
    int node0 = tile*4;
    float pS[4][2], pT[4][2];
#pragma unroll
    for (int ri = 0; ri < 4; ri++)
#pragma unroll
      for (int ci = 0; ci < 2; ci++) {
        int col = cb + ci*16 + n16;
        pS[ri][ci] = PS[(size_t)(node0+ri)*128 + col];
        pT[ri][ci] = PT[(size_t)(node0+ri)*128 + col];
      }

#pragma unroll
    for (int st = 0; st < 2; st++) {
      const unsigned short* W1t = st ? tW1t : sW1t;
      const unsigned short* W2t = st ? tW2t : sW2t;
      const float* sc1 = st ? s1T : s1S;  const float* sh1 = st ? h1T : h1S;
      float (*pp)[2] = st ? pT : pS;
      float* ps  = st ? psT : psS;
      float* ps2 = st ? ps2T : ps2S;
      float* Hmx = st ? HmxT : HmxS;
      float* Hmn = st ? HmnT : HmnS;

      // GEMM1 (bottom half, K=64): h1 = P + D @ W1bot
      f32x4 acc[4][2];
#pragma unroll
      for (int ri = 0; ri < 4; ri++)
#pragma unroll
        for (int ci = 0; ci < 2; ci++)
          acc[ri][ci] = (f32x4){0.f,0.f,0.f,0.f};
#pragma unroll
      for (int ks = 0; ks < 2; ks++) {
        short8 af[4], bf[2];
#pragma unroll
        for (int ri = 0; ri < 4; ri++) {
          int mm = ri*16 + n16;
          af[ri] = *(const short8*)&dlds[mm*64 + ((ks*4+q) ^ (mm & 7))*8];
        }
#pragma unroll
        for (int ci = 0; ci < 2; ci++) {
          int col = cb + ci*16 + n16;
          bf[ci] = *(const short8*)(W1t + col*128 + 64 + (ks*4+q)*8);
        }
#pragma unroll
        for (int ri = 0; ri < 4; ri++)
#pragma unroll
          for (int ci = 0; ci < 2; ci++)
            acc[ri][ci] = __builtin_amdgcn_mfma_f32_16x16x32_bf16(af[ri], bf[ci], acc[ri][ci], 0, 0, 0);
      }
      // bn1 + relu -> a-tile (bf16, swizzled)
#pragma unroll
      for (int ri = 0; ri < 4; ri++)
#pragma unroll
        for (int ci = 0; ci < 2; ci++) {
          int colL = cb + ci*16 + n16;
          int kc8 = colL >> 3;
#pragma unroll
          for (int r = 0; r < 4; r++) {
            float v = acc[ri][ci][r] + pp[ri][ci];
            v = fmaxf(v * sc1[ci] + sh1[ci], 0.f);
            int rowL = ri*16 + q*4 + r;
            int pos = ((kc8 ^ (rowL & 7)) << 3) + (colL & 7);
            atile[rowL*128 + pos] = f2bf(v);
          }
        }
      __syncthreads();
      // GEMM2 (K=128)
      f32x4 acc2[4][2];
#pragma unroll
      for (int ri = 0; ri < 4; ri++)
#pragma unroll
        for (int ci = 0; ci < 2; ci++)
          acc2[ri][ci] = (f32x4){0.f,0.f,0.f,0.f};
#pragma unroll
      for (int ks = 0; ks < 4; ks++) {
        short8 a2[4], bf[2];
#pragma unroll
        for (int ri = 0; ri < 4; ri++) {
          int mm = ri*16 + n16;
          int kc8 = (ks*4 + q) ^ (mm & 7);
          a2[ri] = *(const short8*)&atile[mm*128 + kc8*8];
        }
#pragma unroll
        for (int ci = 0; ci < 2; ci++) {
          int col = cb + ci*16 + n16;
          bf[ci] = *(const short8*)(W2t + col*128 + ks*32 + q*8);
        }
#pragma unroll
        for (int ri = 0; ri < 4; ri++)
#pragma unroll
          for (int ci = 0; ci < 2; ci++)
            acc2[ri][ci] = __builtin_amdgcn_mfma_f32_16x16x32_bf16(a2[ri], bf[ci], acc2[ri][ci], 0, 0, 0);
      }
      // stats2 + per-node max/min over K (pre-BN2)
#pragma unroll
      for (int ri = 0; ri < 4; ri++)
#pragma unroll
        for (int ci = 0; ci < 2; ci++) {
          int col = cb + ci*16 + n16;
          float vmx = -__builtin_inff(), vmn = __builtin_inff();
#pragma unroll
          for (int r = 0; r < 4; r++) {
            float v = acc2[ri][ci][r];
            ps[ci] += v; ps2[ci] += v*v;
            vmx = fmaxf(vmx, v); vmn = fminf(vmn, v);
          }
          vmx = fmaxf(vmx, __shfl_xor(vmx, 16, 64));
          vmx = fmaxf(vmx, __shfl_xor(vmx, 32, 64));
          vmn = fminf(vmn, __shfl_xor(vmn, 16, 64));
          vmn = fminf(vmn, __shfl_xor(vmn, 32, 64));
          if (q == 0) {
            Hmx[(size_t)(node0 + ri)*128 + col] = vmx;
            Hmn[(size_t)(node0 + ri)*128 + col] = vmn;
          }
        }
      if (st == 0) __syncthreads();
    }
  }
#pragma unroll
  for (int ci = 0; ci < 2; ci++) {
    int col = cb + ci*16 + n16;
    float a = psS[ci], a2 = ps2S[ci], b = psT[ci], b2 = ps2T[ci];
    a  += __shfl_xor(a, 16, 64);  a  += __shfl_xor(a, 32, 64);
    a2 += __shfl_xor(a2, 16, 64); a2 += __shfl_xor(a2, 32, 64);
    b  += __shfl_xor(b, 16, 64);  b  += __shfl_xor(b, 32, 64);
    b2 += __shfl_xor(b2, 16, 64); b2 += __shfl_xor(b2, 32, 64);
    if (q == 0) {
      atomicAdd(&statS[col], a);
      atomicAdd(&statS[128 + col], a2);
      atomicAdd(&statT[col], b);
      atomicAdd(&statT[128 + col], b2);
    }
  }
}

// ---------------- final2: bn2+relu via max/min + final linear (K=256) + statF ----------------
// max_k relu(s*h+b) = relu(s*(s>=0?max:min)+b) — affine monotone, relu monotone. Exact.
__global__ __launch_bounds__(256) void final2_kernel(
    const float* __restrict__ HmxS, const float* __restrict__ HmnS,
    const float* __restrict__ HmxT, const float* __restrict__ HmnT,
    const float* __restrict__ affS2, const float* __restrict__ affT2,
    const unsigned short* __restrict__ fWt,
    float* __restrict__ gout, float* __restrict__ statF) {
  __shared__ unsigned short xtile[64*256];
  __shared__ float aff[512];
  int tid = threadIdx.x;
  aff[tid] = affS2[tid & 255];          // tid 0..255 -> affS2[0..255]
  aff[256 + tid] = affT2[tid & 255];
  __syncthreads();
  int node0 = blockIdx.x * 64;
  {
    int r = tid >> 2, part = tid & 3;
    size_t rowoff = (size_t)(node0 + r) * 128;
#pragma unroll
    for (int st = 0; st < 2; st++) {
      const float* Hmx = st ? HmxT : HmxS;
      const float* Hmn = st ? HmnT : HmnS;
      const float* af = &aff[st*256];
#pragma unroll
      for (int g8 = 0; g8 < 4; g8++) {
        int col0 = part*32 + g8*8;
        float4 x0 = *(const float4*)&Hmx[rowoff + col0];
        float4 x1 = *(const float4*)&Hmx[rowoff + col0 + 4];
        float4 n0 = *(const float4*)&Hmn[rowoff + col0];
        float4 n1 = *(const float4*)&Hmn[rowoff + col0 + 4];
        float mx[8] = {x0.x,x0.y,x0.z,x0.w,x1.x,x1.y,x1.z,x1.w};
        float mn[8] = {n0.x,n0.y,n0.z,n0.w,n1.x,n1.y,n1.z,n1.w};
        ushort8 ov;
#pragma unroll
        for (int j = 0; j < 8; j++) {
          int col = col0 + j;
          float sc = af[col], sh = af[128 + col];
          float z = (sc >= 0.f) ? mx[j] : mn[j];
          ov[j] = f2bf(fmaxf(sc*z + sh, 0.f));
        }
        int kc8 = (st*128 + col0) >> 3;
        *(ushort8*)&xtile[r*256 + ((kc8 ^ (r & 7)) << 3)] = ov;
      }
    }
  }
  __syncthreads();
  int wave = tid >> 6, lane = tid & 63;
  int n16 = lane & 15, q = lane >> 4;
  int cb = wave * 32;
  f32x4 acc[4][2];
#pragma unroll
  for (int ri = 0; ri < 4; ri++)
#pragma unroll
    for (int ci = 0; ci < 2; ci++)
      acc[ri][ci] = (f32x4){0.f,0.f,0.f,0.f};
#pragma unroll
  for (int ks = 0; ks < 8; ks++) {
    short8 af[4], bf[2];
#pragma unroll
    for (int ri = 0; ri < 4; ri++) {
      int mm = ri*16 + n16;
      int kc8 = (ks*4 + q) ^ (mm & 7);
      af[ri] = *(const short8*)&xtile[mm*256 + kc8*8];
    }
#pragma unroll
    for (int ci = 0; ci < 2; ci++) {
      int col = cb + ci*16 + n16;
      bf[ci] = *(const short8*)(fWt + col*256 + ks*32 + q*8);
    }
#pragma unroll
    for (int ri = 0; ri < 4; ri++)
#pragma unroll
      for (int ci = 0; ci < 2; ci++)
        acc[ri][ci] = __builtin_amdgcn_mfma_f32_16x16x32_bf16(af[ri], bf[ci], acc[ri][ci], 0, 0, 0);
  }
  float ps[2] = {0,0}, ps2[2] = {0,0};
#pragma unroll
  for (int ri = 0; ri < 4; ri++)
#pragma unroll
    for (int ci = 0; ci < 2; ci++) {
      int col = cb + ci*16 + n16;
#pragma unroll
      for (int r = 0; r < 4; r++) {
        float v = acc[ri][ci][r];
        int row = node0 + ri*16 + q*4 + r;
        gout[(size_t)row*128 + col] = v;
        ps[ci] += v; ps2[ci] += v*v;
      }
    }
#pragma unroll
  for (int ci = 0; ci < 2; ci++) {
    int col = cb + ci*16 + n16;
    float a = ps[ci], a2 = ps2[ci];
    a  += __shfl_xor(a, 16, 64);  a  += __shfl_xor(a, 32, 64);
    a2 += __shfl_xor(a2, 16, 64); a2 += __shfl_xor(a2, 32, 64);
    if (q == 0) {
      atomicAdd(&statF[col], a);
      atomicAdd(&statF[128 + col], a2);
    }
  }
}

// ---------------- finalize BN stats -> (scale, shift) ----------------
__global__ void finalize_kernel(const float* __restrict__ stats,
                                const float* __restrict__ g,
                                const float* __restrict__ be,
                                float* __restrict__ aff, float invcount) {
  int c = threadIdx.x;
  if (c < 128) {
    float mean = stats[c] * invcount;
    float var = stats[128 + c] * invcount - mean*mean;
    float scale = g[c] / sqrtf(var + EPSV);
    aff[c] = scale;
    aff[128 + c] = be[c] - mean * scale;
  }
}

__global__ void apply_bn_kernel(float* __restrict__ out, const float* __restrict__ aff) {
  int i = blockIdx.x * blockDim.x + threadIdx.x;
  if (i < NS*NH) {
    int c = i & 127;
    out[i] = fmaxf(out[i] * aff[c] + aff[128 + c], 0.f);
  }
}

extern "C" void kernel_launch(void* const* d_in, const int* in_sizes, int n_in,
                              void* d_out, int out_size, void* d_ws, size_t ws_size,
                              hipStream_t stream) {
  const float* x   = (const float*)d_in[0];
  const float* sW1 = (const float*)d_in[2];
  const float* sg1 = (const float*)d_in[4];
  const float* sbe1= (const float*)d_in[5];
  const float* sW2 = (const float*)d_in[6];
  const float* sg2 = (const float*)d_in[8];
  const float* sbe2= (const float*)d_in[9];
  const float* tW1 = (const float*)d_in[10];
  const float* tg1 = (const float*)d_in[12];
  const float* tbe1= (const float*)d_in[13];
  const float* tW2 = (const float*)d_in[14];
  const float* tg2 = (const float*)d_in[16];
  const float* tbe2= (const float*)d_in[17];
  const float* fW  = (const float*)d_in[18];
  const float* fg  = (const float*)d_in[20];
  const float* fbe = (const float*)d_in[21];
  float* out = (float*)d_out;

  char* w = (char*)d_ws;
  float* sq = (float*)w;                 w += (size_t)NS*4;
  int* nbr = (int*)w;                    w += (size_t)NSK*4;
  unsigned short* sW1t = (unsigned short*)w; w += 32768;
  unsigned short* sW2t = (unsigned short*)w; w += 32768;
  unsigned short* tW1t = (unsigned short*)w; w += 32768;
  unsigned short* tW2t = (unsigned short*)w; w += 32768;
  unsigned short* fWt  = (unsigned short*)w; w += 65536;
  float* stats = (float*)w;              w += 2560*4;
  unsigned short* xh = (unsigned short*)w; w += (size_t)NS*64*2;
  unsigned short* xl = (unsigned short*)w; w += (size_t)NS*64*2;
  unsigned short* Dg = (unsigned short*)w; w += (size_t)NSK*64*2;
  float* PS = (float*)w;                 w += (size_t)NS*128*4;
  float* PT = (float*)w;                 w += (size_t)NS*128*4;
  float* HmxS = (float*)w;               w += (size_t)NS*128*4;
  float* HmnS = (float*)w;               w += (size_t)NS*128*4;
  float* HmxT = (float*)w;               w += (size_t)NS*128*4;
  float* HmnT = (float*)w;               w += (size_t)NS*128*4;

  float* st_s1 = stats;        float* af_s1 = stats + 256;
  float* st_s2 = stats + 512;  float* af_s2 = stats + 768;
  float* st_t1 = stats + 1024; float* af_t1 = stats + 1280;
  float* st_t2 = stats + 1536; float* af_t2 = stats + 1792;
  float* st_f  = stats + 2048; float* af_f  = stats + 2304;

  hipMemsetAsync(stats, 0, 2560*4, stream);
  prep_weights<<<(4*16384 + 128*256 + 255)/256, 256, 0, stream>>>(
      sW1, sW2, tW1, tW2, fW, sW1t, sW2t, tW1t, tW2t, fWt);
  prep_x<<<NS/256, 256, 0, stream>>>(x, sq, xh, xl);
  knn5_kernel<<<NB*32, 256, 0, stream>>>(xh, xl, sq, nbr);
  pnode_kernel<<<NS/64, 256, 0, stream>>>(x, sW1t, tW1t, PS, PT);
  dstat_kernel<<<2048, 256, 0, stream>>>(x, nbr, sW1t, tW1t, PS, PT, Dg, st_s1, st_t1);

  const float inv1 = 1.f/(float)NSK, invf = 1.f/(float)NS;
  finalize_kernel<<<1,128,0,stream>>>(st_s1, sg1, sbe1, af_s1, inv1);
  finalize_kernel<<<1,128,0,stream>>>(st_t1, tg1, tbe1, af_t1, inv1);
  mlp_mid<<<2048,256,0,stream>>>(Dg, PS, PT, sW1t, sW2t, tW1t, tW2t,
      af_s1, af_t1, st_s2, st_t2, HmxS, HmnS, HmxT, HmnT);
  finalize_kernel<<<1,128,0,stream>>>(st_s2, sg2, sbe2, af_s2, inv1);
  finalize_kernel<<<1,128,0,stream>>>(st_t2, tg2, tbe2, af_t2, inv1);
  final2_kernel<<<NS/64, 256, 0, stream>>>(HmxS, HmnS, HmxT, HmnT,
      af_s2, af_t2, fWt, out, st_f);
  finalize_kernel<<<1,128,0,stream>>>(st_f, fg, fbe, af_f, invf);
  apply_bn_kernel<<<(NS*NH)/256, 256, 0, stream>>>(out, af_f);
}